// Round 1
// baseline (946.129 us; speedup 1.0000x reference)
//
#include <hip/hip_runtime.h>
#include <math.h>

// Problem constants (from reference)
#define NN   20000            // nodes
#define NE   320000           // edges (before self loops)
#define NE2  (NE + NN)        // edges incl. self loops
#define NG   64               // graphs
#define INF_ 6                // input features
#define EDF  2                // edge feature dim
#define NH   4                // heads
#define FD   64               // per-head dim
#define HF   256              // NH*FD
#define FCD  64               // pre-pool MLP dim
#define NCD  2                // classes
#define CAP  128              // max edges whose logits we cache in LDS per node

// ---------------- CSR build ----------------

__global__ void k_count_sum(const int* __restrict__ ei, const float* __restrict__ ea,
                            int* __restrict__ cnt, float* __restrict__ la) {
  int e = blockIdx.x * blockDim.x + threadIdx.x;
  if (e >= NE) return;
  int d = ei[NE + e];                 // dst
  atomicAdd(&cnt[d], 1);
  atomicAdd(&la[2 * d],     ea[2 * e]);
  atomicAdd(&la[2 * d + 1], ea[2 * e + 1]);
}

// Single-block scan: rowptr = exclusive_scan(cnt+1); cursor = rowptr copy;
// also normalize self-loop attrs la /= max(cnt,1).
__global__ void k_scan(const int* __restrict__ cnt, float* __restrict__ la,
                       int* __restrict__ rowptr, int* __restrict__ cursor) {
  __shared__ int sc[1024];
  int t = threadIdx.x;
  const int CH = 20;                  // 1024*20 >= NN
  int base = t * CH;
  int s = 0;
  for (int i = base; i < base + CH && i < NN; ++i) s += cnt[i] + 1;
  sc[t] = s;
  __syncthreads();
  for (int o = 1; o < 1024; o <<= 1) {
    int add = (t >= o) ? sc[t - o] : 0;
    __syncthreads();
    sc[t] += add;
    __syncthreads();
  }
  int run = sc[t] - s;                // exclusive prefix
  for (int i = base; i < base + CH && i < NN; ++i) {
    rowptr[i] = run;
    cursor[i] = run;
    int c = cnt[i];
    run += c + 1;
    float inv = 1.0f / fmaxf((float)c, 1.0f);
    la[2 * i]     *= inv;
    la[2 * i + 1] *= inv;
  }
  if (t == 1023) rowptr[NN] = run;    // thread 1023's base >= NN, run == total
}

__global__ void k_scatter(const int* __restrict__ ei, int* __restrict__ cursor,
                          int* __restrict__ eids) {
  int i = blockIdx.x * blockDim.x + threadIdx.x;
  if (i >= NE2) return;
  int d = (i < NE) ? ei[NE + i] : (i - NE);
  int pos = atomicAdd(&cursor[d], 1);
  eids[pos] = i;
}

// ---------------- layer-0 node transforms (K=6, trivial) ----------------

__global__ void k_l0_transform(const float* __restrict__ x,
                               const float* __restrict__ Wl, const float* __restrict__ bl,
                               const float* __restrict__ Wr, const float* __restrict__ br,
                               float* __restrict__ xl, float* __restrict__ xr) {
  int n = blockIdx.x, c = threadIdx.x;
  float al = bl[c], ar = br[c];
#pragma unroll
  for (int k = 0; k < INF_; ++k) {
    float xv = x[n * INF_ + k];
    al = fmaf(xv, Wl[k * HF + c], al);
    ar = fmaf(xv, Wr[k * HF + c], ar);
  }
  xl[n * HF + c] = al;
  xr[n * HF + c] = ar;
}

// ---------------- layer-1 node transforms: x1(20000x256) @ {Wl1,Wr1}(256x256) ----------------
// 32 rows per block, thread = output column, float4 LDS broadcast reads.

__global__ __launch_bounds__(256) void k_l1_transform(
    const float* __restrict__ x1,
    const float* __restrict__ Wl, const float* __restrict__ bl,
    const float* __restrict__ Wr, const float* __restrict__ br,
    float* __restrict__ xl, float* __restrict__ xr) {
  __shared__ float xs[32 * HF];
  int c = threadIdx.x;
  int row0 = blockIdx.x * 32;
  const float4* s4 = (const float4*)(x1 + (size_t)row0 * HF);
  float4* d4 = (float4*)xs;
#pragma unroll
  for (int i = 0; i < 8; ++i) d4[i * 256 + c] = s4[i * 256 + c];
  __syncthreads();
  float accl[32], accr[32];
#pragma unroll
  for (int r = 0; r < 32; ++r) { accl[r] = 0.f; accr[r] = 0.f; }
  for (int k4 = 0; k4 < HF / 4; ++k4) {
    float wl[4], wr[4];
#pragma unroll
    for (int j = 0; j < 4; ++j) {
      wl[j] = Wl[(k4 * 4 + j) * HF + c];
      wr[j] = Wr[(k4 * 4 + j) * HF + c];
    }
#pragma unroll
    for (int r = 0; r < 32; ++r) {
      float4 xv = *(const float4*)&xs[r * HF + k4 * 4];
      accl[r] = fmaf(xv.x, wl[0], accl[r]);
      accl[r] = fmaf(xv.y, wl[1], accl[r]);
      accl[r] = fmaf(xv.z, wl[2], accl[r]);
      accl[r] = fmaf(xv.w, wl[3], accl[r]);
      accr[r] = fmaf(xv.x, wr[0], accr[r]);
      accr[r] = fmaf(xv.y, wr[1], accr[r]);
      accr[r] = fmaf(xv.z, wr[2], accr[r]);
      accr[r] = fmaf(xv.w, wr[3], accr[r]);
    }
  }
  float blv = bl[c], brv = br[c];
#pragma unroll
  for (int r = 0; r < 32; ++r) {
    xl[(size_t)(row0 + r) * HF + c] = accl[r] + blv;
    xr[(size_t)(row0 + r) * HF + c] = accr[r] + brv;
  }
}

// ---------------- fused GATv2 attention + aggregation + epilogue ----------------
// One block (256 threads) per dst node. Thread c owns channel c; head h = c>>6 = wave id.
// Pass A: per-edge logits (64-lane shfl reduce), per-head max; logits cached in LDS.
// Pass B: w = exp(logit - max); den += w; acc += w * xl[src,c].
// Epilogue L0: elu(acc/den + b0) + x@proj0 -> x1
// Epilogue L1: x2 = elu(.) + x1; z = elu(x2@Wp+bp); atomicAdd into graph pool.

template <bool L0>
__global__ __launch_bounds__(256) void k_agg(
    const float* __restrict__ xl, const float* __restrict__ xr,
    const int* __restrict__ rowptr, const int* __restrict__ eids,
    const int* __restrict__ ei, const float* __restrict__ ea,
    const float* __restrict__ la, const float* __restrict__ We,
    const float* __restrict__ att, const float* __restrict__ bias,
    const float* __restrict__ x, const float* __restrict__ proj0, float* __restrict__ x1out,
    const float* __restrict__ x1in, const float* __restrict__ Wp, const float* __restrict__ bp,
    const int* __restrict__ batch, float* __restrict__ gpool, float* __restrict__ gcnt) {
  __shared__ float xr_s[HF];
  __shared__ float att_s[HF];
  __shared__ float we_s[2 * HF];
  __shared__ float lg_s[CAP * NH];

  int n = blockIdx.x;
  int tid = threadIdx.x;
  int h = tid >> 6;

  xr_s[tid] = xr[(size_t)n * HF + tid];
  att_s[tid] = att[tid];
  we_s[tid] = We[tid];
  we_s[HF + tid] = We[HF + tid];
  __syncthreads();

  int beg = rowptr[n], end = rowptr[n + 1];
  int deg = end - beg;

  float mx = -3.4e38f;
  for (int idx = 0; idx < deg; ++idx) {
    int eid = eids[beg + idx];
    int s; float a0, a1;
    if (eid < NE) {
      s = ei[eid]; a0 = ea[2 * eid]; a1 = ea[2 * eid + 1];
    } else {
      s = eid - NE; a0 = la[2 * s]; a1 = la[2 * s + 1];
    }
    float xlv = xl[(size_t)s * HF + tid];
    float m = xlv + xr_s[tid] + a0 * we_s[tid] + a1 * we_s[HF + tid];
    m = (m > 0.f) ? m : 0.2f * m;               // leaky_relu 0.2
    float t = m * att_s[tid];
#pragma unroll
    for (int o = 32; o > 0; o >>= 1) t += __shfl_xor(t, o, 64);
    if ((tid & 63) == 0 && idx < CAP) lg_s[idx * NH + h] = t;
    mx = fmaxf(mx, t);
  }
  __syncthreads();

  float den = 0.f, acc = 0.f;
  for (int idx = 0; idx < deg; ++idx) {
    int eid = eids[beg + idx];
    int s; float a0, a1;
    if (eid < NE) {
      s = ei[eid]; a0 = ea[2 * eid]; a1 = ea[2 * eid + 1];
    } else {
      s = eid - NE; a0 = la[2 * s]; a1 = la[2 * s + 1];
    }
    float xlv = xl[(size_t)s * HF + tid];
    float t;
    if (idx < CAP) {
      t = lg_s[idx * NH + h];
    } else {                                    // (practically never taken; correctness path)
      float m = xlv + xr_s[tid] + a0 * we_s[tid] + a1 * we_s[HF + tid];
      m = (m > 0.f) ? m : 0.2f * m;
      t = m * att_s[tid];
#pragma unroll
      for (int o = 32; o > 0; o >>= 1) t += __shfl_xor(t, o, 64);
    }
    float w = __expf(t - mx);
    den += w;
    acc = fmaf(w, xlv, acc);
  }

  float ov = acc / den + bias[tid];
  float ev = (ov > 0.f) ? ov : expm1f(ov);      // elu

  if (L0) {
    float r = 0.f;
#pragma unroll
    for (int k = 0; k < INF_; ++k)
      r = fmaf(x[n * INF_ + k], proj0[k * HF + tid], r);
    x1out[(size_t)n * HF + tid] = ev + r;
  } else {
    float x2v = ev + x1in[(size_t)n * HF + tid];
    __syncthreads();                             // done with xr_s / lg_s
    xr_s[tid] = x2v;                             // reuse as x2 row
    __syncthreads();
    // z[j] = elu(sum_c x2[c]*Wp[c,j] + bp[j]); 4 partial sums per j across the 4 waves
    int j = tid & 63, q = tid >> 6;
    float p = 0.f;
    for (int c = q * 64; c < q * 64 + 64; ++c)
      p = fmaf(xr_s[c], Wp[c * FCD + j], p);
    lg_s[tid] = p;
    __syncthreads();
    if (tid < 64) {
      float a = bp[tid] + lg_s[tid] + lg_s[64 + tid] + lg_s[128 + tid] + lg_s[192 + tid];
      float zv = (a > 0.f) ? a : expm1f(a);
      int g = batch[n];
      atomicAdd(&gpool[g * FCD + tid], zv);
      if (tid == 0) atomicAdd(&gcnt[g], 1.0f);
    }
  }
}

// ---------------- final classifier: out[g,k] = (gpool[g]/cnt) @ Wc + bc ----------------

__global__ void k_head(const float* __restrict__ gpool, const float* __restrict__ gcnt,
                       const float* __restrict__ Wc, const float* __restrict__ bc,
                       float* __restrict__ out) {
  int t = threadIdx.x;                 // 128 threads
  int g = t >> 1, k = t & 1;
  float inv = 1.0f / fmaxf(gcnt[g], 1.0f);
  float a = bc[k];
  for (int j = 0; j < FCD; ++j)
    a = fmaf(gpool[g * FCD + j] * inv, Wc[j * NCD + k], a);
  out[g * NCD + k] = a;
}

// ---------------- launch ----------------

extern "C" void kernel_launch(void* const* d_in, const int* in_sizes, int n_in,
                              void* d_out, int out_size, void* d_ws, size_t ws_size,
                              hipStream_t stream) {
  const float* x    = (const float*)d_in[0];
  const int*   ei   = (const int*)d_in[1];    // [2,E] int
  const float* ea   = (const float*)d_in[2];  // [E,2]
  const int*   batch= (const int*)d_in[3];
  const float* Wl0  = (const float*)d_in[4];
  const float* bl0  = (const float*)d_in[5];
  const float* Wr0  = (const float*)d_in[6];
  const float* br0  = (const float*)d_in[7];
  const float* We0  = (const float*)d_in[8];
  const float* att0 = (const float*)d_in[9];
  const float* b0   = (const float*)d_in[10];
  const float* proj0= (const float*)d_in[11];
  const float* Wl1  = (const float*)d_in[12];
  const float* bl1  = (const float*)d_in[13];
  const float* Wr1  = (const float*)d_in[14];
  const float* br1  = (const float*)d_in[15];
  const float* We1  = (const float*)d_in[16];
  const float* att1 = (const float*)d_in[17];
  const float* b1   = (const float*)d_in[18];
  const float* Wp   = (const float*)d_in[19];
  const float* bp   = (const float*)d_in[20];
  const float* Wc   = (const float*)d_in[21];
  const float* bc   = (const float*)d_in[22];
  float* out = (float*)d_out;

  // workspace layout (all 16B aligned)
  char* ws = (char*)d_ws;
  size_t off = 0;
  int*   rowptr = (int*)(ws + off);   off += ((NN + 1) * 4 + 15) / 16 * 16;   // 80016
  int*   cnt    = (int*)(ws + off);   off += (NN * 4 + 15) / 16 * 16;
  int*   cursor = (int*)(ws + off);   off += (NN * 4 + 15) / 16 * 16;
  float* la     = (float*)(ws + off); off += (NN * 2 * 4 + 15) / 16 * 16;
  int*   eids   = (int*)(ws + off);   off += (NE2 * 4 + 15) / 16 * 16;
  float* xl     = (float*)(ws + off); off += (size_t)NN * HF * 4;
  float* xr     = (float*)(ws + off); off += (size_t)NN * HF * 4;
  float* x1     = (float*)(ws + off); off += (size_t)NN * HF * 4;
  float* gpool  = (float*)(ws + off); off += NG * FCD * 4;
  float* gcnt   = (float*)(ws + off); off += NG * 4;
  (void)ws_size; (void)in_sizes; (void)n_in; (void)out_size;

  // zero accumulators (ws is poisoned 0xAA before every call)
  hipMemsetAsync(cnt, 0, NN * 4, stream);
  hipMemsetAsync(la, 0, NN * 2 * 4, stream);
  hipMemsetAsync(gpool, 0, (NG * FCD + NG) * 4, stream);

  // CSR build + self-loop mean attrs
  k_count_sum<<<(NE + 255) / 256, 256, 0, stream>>>(ei, ea, cnt, la);
  k_scan<<<1, 1024, 0, stream>>>(cnt, la, rowptr, cursor);
  k_scatter<<<(NE2 + 255) / 256, 256, 0, stream>>>(ei, cursor, eids);

  // layer 0
  k_l0_transform<<<NN, 256, 0, stream>>>(x, Wl0, bl0, Wr0, br0, xl, xr);
  k_agg<true><<<NN, 256, 0, stream>>>(xl, xr, rowptr, eids, ei, ea, la, We0, att0, b0,
                                      x, proj0, x1,
                                      nullptr, nullptr, nullptr, nullptr, nullptr, nullptr);

  // layer 1
  k_l1_transform<<<NN / 32, 256, 0, stream>>>(x1, Wl1, bl1, Wr1, br1, xl, xr);
  k_agg<false><<<NN, 256, 0, stream>>>(xl, xr, rowptr, eids, ei, ea, la, We1, att1, b1,
                                       nullptr, nullptr, nullptr,
                                       x1, Wp, bp, batch, gpool, gcnt);

  // head
  k_head<<<1, 128, 0, stream>>>(gpool, gcnt, Wc, bc, out);
}

// Round 2
// 751.941 us; speedup vs baseline: 1.2582x; 1.2582x over previous
//
#include <hip/hip_runtime.h>
#include <math.h>

// Problem constants (from reference)
#define NN   20000            // nodes
#define NE   320000           // edges (before self loops)
#define NE2  (NE + NN)        // edges incl. self loops
#define NG   64               // graphs
#define INF_ 6                // input features
#define EDF  2                // edge feature dim
#define NH   4                // heads
#define FD   64               // per-head dim
#define HF   256              // NH*FD
#define FCD  64               // pre-pool MLP dim
#define NCD  2                // classes
#define CAP  256              // max cached edges per node (deg ~ Poisson(16)+1; P(>256) ~ 0)

// ---------------- CSR build ----------------

__global__ void k_count_sum(const int* __restrict__ ei, const float* __restrict__ ea,
                            int* __restrict__ cnt, float* __restrict__ la) {
  int e = blockIdx.x * blockDim.x + threadIdx.x;
  if (e >= NE) return;
  int d = ei[NE + e];                 // dst
  atomicAdd(&cnt[d], 1);
  atomicAdd(&la[2 * d],     ea[2 * e]);
  atomicAdd(&la[2 * d + 1], ea[2 * e + 1]);
}

// Single-block scan: rowptr = exclusive_scan(cnt+1); cursor = rowptr copy;
// also normalize self-loop attrs la /= max(cnt,1).
__global__ void k_scan(const int* __restrict__ cnt, float* __restrict__ la,
                       int* __restrict__ rowptr, int* __restrict__ cursor) {
  __shared__ int sc[1024];
  int t = threadIdx.x;
  const int CH = 20;                  // 1024*20 >= NN
  int base = t * CH;
  int s = 0;
  for (int i = base; i < base + CH && i < NN; ++i) s += cnt[i] + 1;
  sc[t] = s;
  __syncthreads();
  for (int o = 1; o < 1024; o <<= 1) {
    int add = (t >= o) ? sc[t - o] : 0;
    __syncthreads();
    sc[t] += add;
    __syncthreads();
  }
  int run = sc[t] - s;                // exclusive prefix
  for (int i = base; i < base + CH && i < NN; ++i) {
    rowptr[i] = run;
    cursor[i] = run;
    int c = cnt[i];
    run += c + 1;
    float inv = 1.0f / fmaxf((float)c, 1.0f);
    la[2 * i]     *= inv;
    la[2 * i + 1] *= inv;
  }
  if (t == 1023) rowptr[NN] = run;    // thread 1023's base >= NN, run == total
}

// Scatter edge records (src, a0, a1) into CSR order — removes all indirection
// from the hot aggregation kernel.
__global__ void k_scatter(const int* __restrict__ ei, const float* __restrict__ ea,
                          const float* __restrict__ la, int* __restrict__ cursor,
                          float4* __restrict__ rec) {
  int i = blockIdx.x * blockDim.x + threadIdx.x;
  if (i >= NE2) return;
  int s, d; float a0, a1;
  if (i < NE) {
    s = ei[i]; d = ei[NE + i]; a0 = ea[2 * i]; a1 = ea[2 * i + 1];
  } else {
    s = d = i - NE; a0 = la[2 * d]; a1 = la[2 * d + 1];
  }
  int pos = atomicAdd(&cursor[d], 1);
  rec[pos] = make_float4(__int_as_float(s), a0, a1, 0.0f);
}

// ---------------- layer-0 node transforms (K=6, trivial) ----------------

__global__ void k_l0_transform(const float* __restrict__ x,
                               const float* __restrict__ Wl, const float* __restrict__ bl,
                               const float* __restrict__ Wr, const float* __restrict__ br,
                               float* __restrict__ xl, float* __restrict__ xr) {
  int n = blockIdx.x, c = threadIdx.x;
  float al = bl[c], ar = br[c];
#pragma unroll
  for (int k = 0; k < INF_; ++k) {
    float xv = x[n * INF_ + k];
    al = fmaf(xv, Wl[k * HF + c], al);
    ar = fmaf(xv, Wr[k * HF + c], ar);
  }
  xl[n * HF + c] = al;
  xr[n * HF + c] = ar;
}

// ---------------- layer-1 node transforms: x1(20000x256) @ {Wl1,Wr1}(256x256) ----------------

__global__ __launch_bounds__(256) void k_l1_transform(
    const float* __restrict__ x1,
    const float* __restrict__ Wl, const float* __restrict__ bl,
    const float* __restrict__ Wr, const float* __restrict__ br,
    float* __restrict__ xl, float* __restrict__ xr) {
  __shared__ float xs[32 * HF];
  int c = threadIdx.x;
  int row0 = blockIdx.x * 32;
  const float4* s4 = (const float4*)(x1 + (size_t)row0 * HF);
  float4* d4 = (float4*)xs;
#pragma unroll
  for (int i = 0; i < 8; ++i) d4[i * 256 + c] = s4[i * 256 + c];
  __syncthreads();
  float accl[32], accr[32];
#pragma unroll
  for (int r = 0; r < 32; ++r) { accl[r] = 0.f; accr[r] = 0.f; }
  for (int k4 = 0; k4 < HF / 4; ++k4) {
    float wl[4], wr[4];
#pragma unroll
    for (int j = 0; j < 4; ++j) {
      wl[j] = Wl[(k4 * 4 + j) * HF + c];
      wr[j] = Wr[(k4 * 4 + j) * HF + c];
    }
#pragma unroll
    for (int r = 0; r < 32; ++r) {
      float4 xv = *(const float4*)&xs[r * HF + k4 * 4];
      accl[r] = fmaf(xv.x, wl[0], accl[r]);
      accl[r] = fmaf(xv.y, wl[1], accl[r]);
      accl[r] = fmaf(xv.z, wl[2], accl[r]);
      accl[r] = fmaf(xv.w, wl[3], accl[r]);
      accr[r] = fmaf(xv.x, wr[0], accr[r]);
      accr[r] = fmaf(xv.y, wr[1], accr[r]);
      accr[r] = fmaf(xv.z, wr[2], accr[r]);
      accr[r] = fmaf(xv.w, wr[3], accr[r]);
    }
  }
  float blv = bl[c], brv = br[c];
#pragma unroll
  for (int r = 0; r < 32; ++r) {
    xl[(size_t)(row0 + r) * HF + c] = accl[r] + blv;
    xr[(size_t)(row0 + r) * HF + c] = accr[r] + brv;
  }
}

// ---------------- fused GATv2 attention + aggregation + epilogue ----------------
// One block (256 threads = 4 waves) per dst node.
// Pass A: wave-per-edge (4 edges in flight); each wave computes the 4 head
//         logits for its edge via 64-lane butterfly; logits -> LDS.
// Softmax: per head, max + exp + den from LDS-cached logits (weights in place).
// Pass B: thread-per-channel, unrolled x4 independent gathers of xl[src].
// Epilogue L0: elu(acc/den + b0) + x@proj0 -> x1
// Epilogue L1: x2 = elu(.) + x1; z = elu(x2@Wp+bp); atomicAdd into graph pool.

template <bool L0>
__global__ __launch_bounds__(256) void k_agg(
    const float* __restrict__ xl, const float* __restrict__ xr,
    const int* __restrict__ rowptr, const float4* __restrict__ rec,
    const float* __restrict__ att, const float* __restrict__ We,
    const float* __restrict__ bias,
    const float* __restrict__ x, const float* __restrict__ proj0, float* __restrict__ x1out,
    const float* __restrict__ x1in, const float* __restrict__ Wp, const float* __restrict__ bp,
    const int* __restrict__ batch, float* __restrict__ gpool, float* __restrict__ gcnt) {
  __shared__ float xr_s[HF];
  __shared__ float att_s[HF];
  __shared__ float we_s[2 * HF];
  __shared__ float4 rec_s[CAP];
  __shared__ float4 lg4_s[CAP];      // logits then softmax weights, [idx].{x,y,z,w}=heads
  __shared__ float den_s[NH];
  float* lg_s = (float*)lg4_s;

  int n = blockIdx.x;
  int tid = threadIdx.x;
  int wv = tid >> 6;                 // wave id 0..3
  int lane = tid & 63;

  xr_s[tid] = xr[(size_t)n * HF + tid];
  att_s[tid] = att[tid];
  we_s[tid] = We[tid];
  we_s[HF + tid] = We[HF + tid];

  int beg = rowptr[n];
  int deg = rowptr[n + 1] - beg;
  int degc = (deg < CAP) ? deg : CAP;   // deg > CAP statistically impossible here

  for (int i = tid; i < degc; i += 256) rec_s[i] = rec[beg + i];
  __syncthreads();

  // ---- Pass A: logits, wave-per-edge ----
  for (int base = 0; base < degc; base += 4) {
    int idx = base + wv;
    float t[NH] = {0.f, 0.f, 0.f, 0.f};
    if (idx < degc) {
      float4 r = rec_s[idx];
      const float* xlr = xl + (size_t)__float_as_int(r.x) * HF;
#pragma unroll
      for (int h = 0; h < NH; ++h) {
        int c = h * 64 + lane;
        float m = xlr[c] + xr_s[c] + r.y * we_s[c] + r.z * we_s[HF + c];
        m = (m > 0.f) ? m : 0.2f * m;          // leaky_relu 0.2
        t[h] = m * att_s[c];
      }
    }
#pragma unroll
    for (int o = 32; o; o >>= 1) {
#pragma unroll
      for (int h = 0; h < NH; ++h) t[h] += __shfl_xor(t[h], o, 64);
    }
    if (lane == 0 && idx < degc) lg4_s[idx] = make_float4(t[0], t[1], t[2], t[3]);
  }
  __syncthreads();

  // ---- softmax: per head (wave h), max + exp + den over LDS logits ----
  {
    int h = wv;
    float mx = -3.4e38f;
    for (int idx = lane; idx < degc; idx += 64) mx = fmaxf(mx, lg_s[idx * 4 + h]);
#pragma unroll
    for (int o = 32; o; o >>= 1) mx = fmaxf(mx, __shfl_xor(mx, o, 64));
    float dn = 0.f;
    for (int idx = lane; idx < degc; idx += 64) {
      float w = __expf(lg_s[idx * 4 + h] - mx);
      lg_s[idx * 4 + h] = w;
      dn += w;
    }
#pragma unroll
    for (int o = 32; o; o >>= 1) dn += __shfl_xor(dn, o, 64);
    if (lane == 0) den_s[h] = dn;
  }
  __syncthreads();

  // ---- Pass B: weighted aggregation, thread-per-channel, x4 gathers in flight ----
  int h = wv;
  float acc = 0.f;
  int idx = 0;
  for (; idx + 4 <= degc; idx += 4) {
    int s0 = __float_as_int(rec_s[idx + 0].x);
    int s1 = __float_as_int(rec_s[idx + 1].x);
    int s2 = __float_as_int(rec_s[idx + 2].x);
    int s3 = __float_as_int(rec_s[idx + 3].x);
    float w0 = lg_s[(idx + 0) * 4 + h];
    float w1 = lg_s[(idx + 1) * 4 + h];
    float w2 = lg_s[(idx + 2) * 4 + h];
    float w3 = lg_s[(idx + 3) * 4 + h];
    float v0 = xl[(size_t)s0 * HF + tid];
    float v1 = xl[(size_t)s1 * HF + tid];
    float v2 = xl[(size_t)s2 * HF + tid];
    float v3 = xl[(size_t)s3 * HF + tid];
    acc = fmaf(w0, v0, acc);
    acc = fmaf(w1, v1, acc);
    acc = fmaf(w2, v2, acc);
    acc = fmaf(w3, v3, acc);
  }
  for (; idx < degc; ++idx) {
    int s0 = __float_as_int(rec_s[idx].x);
    acc = fmaf(lg_s[idx * 4 + h], xl[(size_t)s0 * HF + tid], acc);
  }

  float ov = acc / den_s[h] + bias[tid];
  float ev = (ov > 0.f) ? ov : expm1f(ov);      // elu

  if (L0) {
    float r = 0.f;
#pragma unroll
    for (int k = 0; k < INF_; ++k)
      r = fmaf(x[n * INF_ + k], proj0[k * HF + tid], r);
    x1out[(size_t)n * HF + tid] = ev + r;
  } else {
    float x2v = ev + x1in[(size_t)n * HF + tid];
    __syncthreads();                             // done with xr_s / lg_s
    xr_s[tid] = x2v;                             // reuse as x2 row
    __syncthreads();
    // z[j] = elu(sum_c x2[c]*Wp[c,j] + bp[j]); 4 partial sums per j across the 4 waves
    int j = tid & 63, q = tid >> 6;
    float p = 0.f;
    for (int c = q * 64; c < q * 64 + 64; ++c)
      p = fmaf(xr_s[c], Wp[c * FCD + j], p);
    lg_s[tid] = p;
    __syncthreads();
    if (tid < 64) {
      float a = bp[tid] + lg_s[tid] + lg_s[64 + tid] + lg_s[128 + tid] + lg_s[192 + tid];
      float zv = (a > 0.f) ? a : expm1f(a);
      int g = batch[n];
      atomicAdd(&gpool[g * FCD + tid], zv);
      if (tid == 0) atomicAdd(&gcnt[g], 1.0f);
    }
  }
}

// ---------------- final classifier: out[g,k] = (gpool[g]/cnt) @ Wc + bc ----------------

__global__ void k_head(const float* __restrict__ gpool, const float* __restrict__ gcnt,
                       const float* __restrict__ Wc, const float* __restrict__ bc,
                       float* __restrict__ out) {
  int t = threadIdx.x;                 // 128 threads
  int g = t >> 1, k = t & 1;
  float inv = 1.0f / fmaxf(gcnt[g], 1.0f);
  float a = bc[k];
  for (int j = 0; j < FCD; ++j)
    a = fmaf(gpool[g * FCD + j] * inv, Wc[j * NCD + k], a);
  out[g * NCD + k] = a;
}

// ---------------- launch ----------------

extern "C" void kernel_launch(void* const* d_in, const int* in_sizes, int n_in,
                              void* d_out, int out_size, void* d_ws, size_t ws_size,
                              hipStream_t stream) {
  const float* x    = (const float*)d_in[0];
  const int*   ei   = (const int*)d_in[1];    // [2,E] int
  const float* ea   = (const float*)d_in[2];  // [E,2]
  const int*   batch= (const int*)d_in[3];
  const float* Wl0  = (const float*)d_in[4];
  const float* bl0  = (const float*)d_in[5];
  const float* Wr0  = (const float*)d_in[6];
  const float* br0  = (const float*)d_in[7];
  const float* We0  = (const float*)d_in[8];
  const float* att0 = (const float*)d_in[9];
  const float* b0   = (const float*)d_in[10];
  const float* proj0= (const float*)d_in[11];
  const float* Wl1  = (const float*)d_in[12];
  const float* bl1  = (const float*)d_in[13];
  const float* Wr1  = (const float*)d_in[14];
  const float* br1  = (const float*)d_in[15];
  const float* We1  = (const float*)d_in[16];
  const float* att1 = (const float*)d_in[17];
  const float* b1   = (const float*)d_in[18];
  const float* Wp   = (const float*)d_in[19];
  const float* bp   = (const float*)d_in[20];
  const float* Wc   = (const float*)d_in[21];
  const float* bc   = (const float*)d_in[22];
  float* out = (float*)d_out;

  // workspace layout (all 16B aligned)
  char* ws = (char*)d_ws;
  size_t off = 0;
  int*   rowptr = (int*)(ws + off);   off += ((NN + 1) * 4 + 15) / 16 * 16;
  int*   cnt    = (int*)(ws + off);   off += (NN * 4 + 15) / 16 * 16;
  int*   cursor = (int*)(ws + off);   off += (NN * 4 + 15) / 16 * 16;
  float* la     = (float*)(ws + off); off += (NN * 2 * 4 + 15) / 16 * 16;
  float4* rec   = (float4*)(ws + off); off += (size_t)NE2 * 16;
  float* xl     = (float*)(ws + off); off += (size_t)NN * HF * 4;
  float* xr     = (float*)(ws + off); off += (size_t)NN * HF * 4;
  float* x1     = (float*)(ws + off); off += (size_t)NN * HF * 4;
  float* gpool  = (float*)(ws + off); off += NG * FCD * 4;
  float* gcnt   = (float*)(ws + off); off += NG * 4;
  (void)ws_size; (void)in_sizes; (void)n_in; (void)out_size;

  // zero accumulators (ws is poisoned 0xAA before every call)
  hipMemsetAsync(cnt, 0, NN * 4, stream);
  hipMemsetAsync(la, 0, NN * 2 * 4, stream);
  hipMemsetAsync(gpool, 0, (NG * FCD + NG) * 4, stream);

  // CSR build + self-loop mean attrs + edge records
  k_count_sum<<<(NE + 255) / 256, 256, 0, stream>>>(ei, ea, cnt, la);
  k_scan<<<1, 1024, 0, stream>>>(cnt, la, rowptr, cursor);
  k_scatter<<<(NE2 + 255) / 256, 256, 0, stream>>>(ei, ea, la, cursor, rec);

  // layer 0
  k_l0_transform<<<NN, 256, 0, stream>>>(x, Wl0, bl0, Wr0, br0, xl, xr);
  k_agg<true><<<NN, 256, 0, stream>>>(xl, xr, rowptr, rec, att0, We0, b0,
                                      x, proj0, x1,
                                      nullptr, nullptr, nullptr, nullptr, nullptr, nullptr);

  // layer 1
  k_l1_transform<<<NN / 32, 256, 0, stream>>>(x1, Wl1, bl1, Wr1, br1, xl, xr);
  k_agg<false><<<NN, 256, 0, stream>>>(xl, xr, rowptr, rec, att1, We1, b1,
                                       nullptr, nullptr, nullptr,
                                       x1, Wp, bp, batch, gpool, gcnt);

  // head
  k_head<<<1, 128, 0, stream>>>(gpool, gcnt, Wc, bc, out);
}

// Round 3
// 525.764 us; speedup vs baseline: 1.7995x; 1.4302x over previous
//
#include <hip/hip_runtime.h>
#include <math.h>

// Problem constants (from reference)
#define NN   20000            // nodes
#define NE   320000           // edges (before self loops)
#define NE2  (NE + NN)        // edges incl. self loops
#define NG   64               // graphs
#define INF_ 6                // input features
#define EDF  2                // edge feature dim
#define NH   4                // heads
#define FD   64               // per-head dim
#define HF   256              // NH*FD
#define FCD  64               // pre-pool MLP dim
#define NCD  2                // classes

// ---------------- CSR build ----------------

__global__ void k_count_sum(const int* __restrict__ ei, const float* __restrict__ ea,
                            int* __restrict__ cnt, float* __restrict__ la) {
  int e = blockIdx.x * blockDim.x + threadIdx.x;
  if (e >= NE) return;
  int d = ei[NE + e];                 // dst
  atomicAdd(&cnt[d], 1);
  atomicAdd(&la[2 * d],     ea[2 * e]);
  atomicAdd(&la[2 * d + 1], ea[2 * e + 1]);
}

// Single-block scan: rowptr = exclusive_scan(cnt); cursor = rowptr copy;
// also normalize self-loop attrs la /= max(cnt,1).
__global__ void k_scan(const int* __restrict__ cnt, float* __restrict__ la,
                       int* __restrict__ rowptr, int* __restrict__ cursor) {
  __shared__ int sc[1024];
  int t = threadIdx.x;
  const int CH = 20;                  // 1024*20 >= NN
  int base = t * CH;
  int s = 0;
  for (int i = base; i < base + CH && i < NN; ++i) s += cnt[i] + 1;
  sc[t] = s;
  __syncthreads();
  for (int o = 1; o < 1024; o <<= 1) {
    int add = (t >= o) ? sc[t - o] : 0;
    __syncthreads();
    sc[t] += add;
    __syncthreads();
  }
  int run = sc[t] - s;                // exclusive prefix
  for (int i = base; i < base + CH && i < NN; ++i) {
    rowptr[i] = run;
    cursor[i] = run;
    int c = cnt[i];
    run += c + 1;
    float inv = 1.0f / fmaxf((float)c, 1.0f);
    la[2 * i]     *= inv;
    la[2 * i + 1] *= inv;
  }
  if (t == 1023) rowptr[NN] = run;    // thread 1023's base >= NN, run == total
}

// Scatter edge records (src, a0, a1) into CSR order.
__global__ void k_scatter(const int* __restrict__ ei, const float* __restrict__ ea,
                          const float* __restrict__ la, int* __restrict__ cursor,
                          float4* __restrict__ rec) {
  int i = blockIdx.x * blockDim.x + threadIdx.x;
  if (i >= NE2) return;
  int s, d; float a0, a1;
  if (i < NE) {
    s = ei[i]; d = ei[NE + i]; a0 = ea[2 * i]; a1 = ea[2 * i + 1];
  } else {
    s = d = i - NE; a0 = la[2 * d]; a1 = la[2 * d + 1];
  }
  int pos = atomicAdd(&cursor[d], 1);
  rec[pos] = make_float4(__int_as_float(s), a0, a1, 0.0f);
}

// ---------------- layer-0 node transforms (K=6, trivial) ----------------

__global__ void k_l0_transform(const float* __restrict__ x,
                               const float* __restrict__ Wl, const float* __restrict__ bl,
                               const float* __restrict__ Wr, const float* __restrict__ br,
                               float* __restrict__ xl, float* __restrict__ xr) {
  int n = blockIdx.x, c = threadIdx.x;
  float al = bl[c], ar = br[c];
#pragma unroll
  for (int k = 0; k < INF_; ++k) {
    float xv = x[n * INF_ + k];
    al = fmaf(xv, Wl[k * HF + c], al);
    ar = fmaf(xv, Wr[k * HF + c], ar);
  }
  xl[n * HF + c] = al;
  xr[n * HF + c] = ar;
}

// ---------------- layer-1 node transforms: x1(20000x256) @ {Wl1,Wr1}(256x256) ----------------

__global__ __launch_bounds__(256) void k_l1_transform(
    const float* __restrict__ x1,
    const float* __restrict__ Wl, const float* __restrict__ bl,
    const float* __restrict__ Wr, const float* __restrict__ br,
    float* __restrict__ xl, float* __restrict__ xr) {
  __shared__ float xs[32 * HF];
  int c = threadIdx.x;
  int row0 = blockIdx.x * 32;
  const float4* s4 = (const float4*)(x1 + (size_t)row0 * HF);
  float4* d4 = (float4*)xs;
#pragma unroll
  for (int i = 0; i < 8; ++i) d4[i * 256 + c] = s4[i * 256 + c];
  __syncthreads();
  float accl[32], accr[32];
#pragma unroll
  for (int r = 0; r < 32; ++r) { accl[r] = 0.f; accr[r] = 0.f; }
  for (int k4 = 0; k4 < HF / 4; ++k4) {
    float wl[4], wr[4];
#pragma unroll
    for (int j = 0; j < 4; ++j) {
      wl[j] = Wl[(k4 * 4 + j) * HF + c];
      wr[j] = Wr[(k4 * 4 + j) * HF + c];
    }
#pragma unroll
    for (int r = 0; r < 32; ++r) {
      float4 xv = *(const float4*)&xs[r * HF + k4 * 4];
      accl[r] = fmaf(xv.x, wl[0], accl[r]);
      accl[r] = fmaf(xv.y, wl[1], accl[r]);
      accl[r] = fmaf(xv.z, wl[2], accl[r]);
      accl[r] = fmaf(xv.w, wl[3], accl[r]);
      accr[r] = fmaf(xv.x, wr[0], accr[r]);
      accr[r] = fmaf(xv.y, wr[1], accr[r]);
      accr[r] = fmaf(xv.z, wr[2], accr[r]);
      accr[r] = fmaf(xv.w, wr[3], accr[r]);
    }
  }
  float blv = bl[c], brv = br[c];
#pragma unroll
  for (int r = 0; r < 32; ++r) {
    xl[(size_t)(row0 + r) * HF + c] = accl[r] + blv;
    xr[(size_t)(row0 + r) * HF + c] = accr[r] + brv;
  }
}

// ---------------- fused GATv2: single-pass online-softmax, one WAVE per node ----------------
// Lane owns 4 contiguous channels (float4); head h = lane>>4.
// Per edge: one coalesced 1KB row gather (used for BOTH logit and aggregation),
// 4-step shfl_xor butterfly for the per-head logit, online-softmax rescale.
// Edge records held in registers (lane e holds rec[beg+e]); depth-1 prefetch.
// No LDS, no __syncthreads, wave-uniform control flow.

template <bool L0>
__global__ __launch_bounds__(256) void k_agg(
    const float* __restrict__ xl, const float* xr_,         // no restrict: x2out aliases
    const int* __restrict__ rowptr, const float4* __restrict__ rec,
    const float* __restrict__ att, const float* __restrict__ We,
    const float* __restrict__ bias,
    const float* __restrict__ x, const float* __restrict__ proj0,
    float* __restrict__ x1out,
    const float* __restrict__ x1in, float* x2out) {
  int wid = (blockIdx.x * 256 + threadIdx.x) >> 6;
  if (wid >= NN) return;
  int lane = threadIdx.x & 63;
  int n = wid;
  int cb = lane << 2;                    // channel base (0..252)

  float4 xr4 = *(const float4*)&xr_[(size_t)n * HF + cb];
  float4 at4 = *(const float4*)&att[cb];
  float4 w04 = *(const float4*)&We[cb];
  float4 w14 = *(const float4*)&We[HF + cb];

  int beg = rowptr[n];
  int deg = rowptr[n + 1] - beg;

  float mx = -3.4e38f, den = 0.f;
  float4 acc = make_float4(0.f, 0.f, 0.f, 0.f);

  for (int chunk = 0; chunk < deg; chunk += 64) {
    int m = min(64, deg - chunk);
    float4 r = make_float4(0.f, 0.f, 0.f, 0.f);
    if (lane < m) r = rec[beg + chunk + lane];
    int rs = __float_as_int(r.x);

    // prefetch edge 0
    int   sC  = __shfl(rs,  0, 64);
    float a0C = __shfl(r.y, 0, 64);
    float a1C = __shfl(r.z, 0, 64);
    float4 vC = *(const float4*)&xl[(size_t)sC * HF + cb];

    for (int e = 0; e < m; ++e) {
      int sN = sC; float a0N = a0C, a1N = a1C;
      float4 vN = vC;
      if (e + 1 < m) {
        sN  = __shfl(rs,  e + 1, 64);
        a0N = __shfl(r.y, e + 1, 64);
        a1N = __shfl(r.z, e + 1, 64);
        vN = *(const float4*)&xl[(size_t)sN * HF + cb];
      }
      float4 mm;
      mm.x = vC.x + xr4.x + a0C * w04.x + a1C * w14.x;
      mm.y = vC.y + xr4.y + a0C * w04.y + a1C * w14.y;
      mm.z = vC.z + xr4.z + a0C * w04.z + a1C * w14.z;
      mm.w = vC.w + xr4.w + a0C * w04.w + a1C * w14.w;
      mm.x = (mm.x > 0.f) ? mm.x : 0.2f * mm.x;      // leaky_relu 0.2
      mm.y = (mm.y > 0.f) ? mm.y : 0.2f * mm.y;
      mm.z = (mm.z > 0.f) ? mm.z : 0.2f * mm.z;
      mm.w = (mm.w > 0.f) ? mm.w : 0.2f * mm.w;
      float t = mm.x * at4.x;
      t = fmaf(mm.y, at4.y, t);
      t = fmaf(mm.z, at4.z, t);
      t = fmaf(mm.w, at4.w, t);
      // per-head reduction over the 16-lane group
      t += __shfl_xor(t, 1, 64);
      t += __shfl_xor(t, 2, 64);
      t += __shfl_xor(t, 4, 64);
      t += __shfl_xor(t, 8, 64);
      // online softmax update
      float mn  = fmaxf(mx, t);
      float sc_ = __expf(mx - mn);     // exp(-inf)=0 handles first edge
      float w   = __expf(t - mn);
      den   = fmaf(den, sc_, w);
      acc.x = fmaf(acc.x, sc_, w * vC.x);
      acc.y = fmaf(acc.y, sc_, w * vC.y);
      acc.z = fmaf(acc.z, sc_, w * vC.z);
      acc.w = fmaf(acc.w, sc_, w * vC.w);
      mx = mn;
      vC = vN; a0C = a0N; a1C = a1N; sC = sN;
    }
  }

  float inv = 1.0f / den;
  float4 b4 = *(const float4*)&bias[cb];
  float4 o;
  o.x = fmaf(acc.x, inv, b4.x);
  o.y = fmaf(acc.y, inv, b4.y);
  o.z = fmaf(acc.z, inv, b4.z);
  o.w = fmaf(acc.w, inv, b4.w);
  o.x = (o.x > 0.f) ? o.x : expm1f(o.x);            // elu
  o.y = (o.y > 0.f) ? o.y : expm1f(o.y);
  o.z = (o.z > 0.f) ? o.z : expm1f(o.z);
  o.w = (o.w > 0.f) ? o.w : expm1f(o.w);

  if (L0) {
    float4 rr = make_float4(0.f, 0.f, 0.f, 0.f);
#pragma unroll
    for (int k = 0; k < INF_; ++k) {
      float xv = x[n * INF_ + k];                    // wave-uniform -> scalar load
      float4 p = *(const float4*)&proj0[k * HF + cb];
      rr.x = fmaf(xv, p.x, rr.x);
      rr.y = fmaf(xv, p.y, rr.y);
      rr.z = fmaf(xv, p.z, rr.z);
      rr.w = fmaf(xv, p.w, rr.w);
    }
    o.x += rr.x; o.y += rr.y; o.z += rr.z; o.w += rr.w;
    *(float4*)&x1out[(size_t)n * HF + cb] = o;
  } else {
    float4 x1v = *(const float4*)&x1in[(size_t)n * HF + cb];
    o.x += x1v.x; o.y += x1v.y; o.z += x1v.z; o.w += x1v.w;
    *(float4*)&x2out[(size_t)n * HF + cb] = o;       // x2out aliases xr_ row n: safe (own row, after read)
  }
}

// ---------------- pre-pool MLP + graph pooling: z=elu(x2@Wp+bp); gpool += z ----------------

__global__ __launch_bounds__(256) void k_pool(
    const float* __restrict__ x2, const float* __restrict__ Wp,
    const float* __restrict__ bp, const int* __restrict__ batch,
    float* __restrict__ gpool) {
  __shared__ float xs[32 * HF];
  __shared__ int gid_s[32];
  int t = threadIdx.x;
  int row0 = blockIdx.x * 32;
  const float4* s4 = (const float4*)(x2 + (size_t)row0 * HF);
  float4* d4 = (float4*)xs;
#pragma unroll
  for (int i = 0; i < 8; ++i) d4[i * 256 + t] = s4[i * 256 + t];
  if (t < 32) gid_s[t] = batch[row0 + t];
  __syncthreads();
  int j = t & 63, rg = t >> 6;          // thread: col j, rows rg*8..rg*8+7
  float acc[8];
#pragma unroll
  for (int rr = 0; rr < 8; ++rr) acc[rr] = 0.f;
  for (int k4 = 0; k4 < HF / 4; ++k4) {
    float w0 = Wp[(k4 * 4 + 0) * FCD + j];
    float w1 = Wp[(k4 * 4 + 1) * FCD + j];
    float w2 = Wp[(k4 * 4 + 2) * FCD + j];
    float w3 = Wp[(k4 * 4 + 3) * FCD + j];
#pragma unroll
    for (int rr = 0; rr < 8; ++rr) {
      float4 xv = *(const float4*)&xs[(rg * 8 + rr) * HF + k4 * 4];
      acc[rr] = fmaf(xv.x, w0, acc[rr]);
      acc[rr] = fmaf(xv.y, w1, acc[rr]);
      acc[rr] = fmaf(xv.z, w2, acc[rr]);
      acc[rr] = fmaf(xv.w, w3, acc[rr]);
    }
  }
  float b = bp[j];
#pragma unroll
  for (int rr = 0; rr < 8; ++rr) {
    float a = acc[rr] + b;
    float z = (a > 0.f) ? a : expm1f(a);
    atomicAdd(&gpool[gid_s[rg * 8 + rr] * FCD + j], z);
  }
}

// ---------------- final classifier: out[g,k] = (gpool[g]/cnt[g]) @ Wc + bc ----------------
// count[g] via binary search on the SORTED batch array (no atomics needed).

__global__ void k_head(const float* __restrict__ gpool, const int* __restrict__ batch,
                       const float* __restrict__ Wc, const float* __restrict__ bc,
                       float* __restrict__ out) {
  int t = threadIdx.x;                 // 128 threads
  int g = t >> 1, k = t & 1;
  int lo = 0, hi = NN;
  while (lo < hi) { int mid = (lo + hi) >> 1; if (batch[mid] < g) lo = mid + 1; else hi = mid; }
  int c0 = lo;
  lo = 0; hi = NN;
  while (lo < hi) { int mid = (lo + hi) >> 1; if (batch[mid] < g + 1) lo = mid + 1; else hi = mid; }
  int c1 = lo;
  float inv = 1.0f / fmaxf((float)(c1 - c0), 1.0f);
  float a = bc[k];
  for (int j = 0; j < FCD; ++j)
    a = fmaf(gpool[g * FCD + j] * inv, Wc[j * NCD + k], a);
  out[g * NCD + k] = a;
}

// ---------------- launch ----------------

extern "C" void kernel_launch(void* const* d_in, const int* in_sizes, int n_in,
                              void* d_out, int out_size, void* d_ws, size_t ws_size,
                              hipStream_t stream) {
  const float* x    = (const float*)d_in[0];
  const int*   ei   = (const int*)d_in[1];    // [2,E] int
  const float* ea   = (const float*)d_in[2];  // [E,2]
  const int*   batch= (const int*)d_in[3];
  const float* Wl0  = (const float*)d_in[4];
  const float* bl0  = (const float*)d_in[5];
  const float* Wr0  = (const float*)d_in[6];
  const float* br0  = (const float*)d_in[7];
  const float* We0  = (const float*)d_in[8];
  const float* att0 = (const float*)d_in[9];
  const float* b0   = (const float*)d_in[10];
  const float* proj0= (const float*)d_in[11];
  const float* Wl1  = (const float*)d_in[12];
  const float* bl1  = (const float*)d_in[13];
  const float* Wr1  = (const float*)d_in[14];
  const float* br1  = (const float*)d_in[15];
  const float* We1  = (const float*)d_in[16];
  const float* att1 = (const float*)d_in[17];
  const float* b1   = (const float*)d_in[18];
  const float* Wp   = (const float*)d_in[19];
  const float* bp   = (const float*)d_in[20];
  const float* Wc   = (const float*)d_in[21];
  const float* bc   = (const float*)d_in[22];
  float* out = (float*)d_out;

  // workspace layout (all 16B aligned)
  char* ws = (char*)d_ws;
  size_t off = 0;
  int*   rowptr = (int*)(ws + off);   off += ((NN + 1) * 4 + 15) / 16 * 16;
  int*   cnt    = (int*)(ws + off);   off += (NN * 4 + 15) / 16 * 16;
  int*   cursor = (int*)(ws + off);   off += (NN * 4 + 15) / 16 * 16;
  float* la     = (float*)(ws + off); off += (NN * 2 * 4 + 15) / 16 * 16;
  float4* rec   = (float4*)(ws + off); off += (size_t)NE2 * 16;
  float* xl     = (float*)(ws + off); off += (size_t)NN * HF * 4;
  float* xr     = (float*)(ws + off); off += (size_t)NN * HF * 4;
  float* x1     = (float*)(ws + off); off += (size_t)NN * HF * 4;
  float* gpool  = (float*)(ws + off); off += NG * FCD * 4;
  float* x2     = xr;                  // alias: safe (each wave writes only its own row, after reading it)
  (void)ws_size; (void)in_sizes; (void)n_in; (void)out_size;

  // zero accumulators (ws is poisoned 0xAA before every call)
  hipMemsetAsync(cnt, 0, NN * 4, stream);
  hipMemsetAsync(la, 0, NN * 2 * 4, stream);
  hipMemsetAsync(gpool, 0, NG * FCD * 4, stream);

  // CSR build + self-loop mean attrs + edge records
  k_count_sum<<<(NE + 255) / 256, 256, 0, stream>>>(ei, ea, cnt, la);
  k_scan<<<1, 1024, 0, stream>>>(cnt, la, rowptr, cursor);
  k_scatter<<<(NE2 + 255) / 256, 256, 0, stream>>>(ei, ea, la, cursor, rec);

  // layer 0
  k_l0_transform<<<NN, 256, 0, stream>>>(x, Wl0, bl0, Wr0, br0, xl, xr);
  k_agg<true><<<(NN * 64 + 255) / 256, 256, 0, stream>>>(
      xl, xr, rowptr, rec, att0, We0, b0, x, proj0, x1, nullptr, nullptr);

  // layer 1
  k_l1_transform<<<NN / 32, 256, 0, stream>>>(x1, Wl1, bl1, Wr1, br1, xl, xr);
  k_agg<false><<<(NN * 64 + 255) / 256, 256, 0, stream>>>(
      xl, xr, rowptr, rec, att1, We1, b1, nullptr, nullptr, nullptr, x1, x2);

  // pre-pool MLP + pooling, then classifier
  k_pool<<<NN / 32, 256, 0, stream>>>(x2, Wp, bp, batch, gpool);
  k_head<<<1, 128, 0, stream>>>(gpool, batch, Wc, bc, out);
}

// Round 4
// 484.950 us; speedup vs baseline: 1.9510x; 1.0842x over previous
//
#include <hip/hip_runtime.h>
#include <math.h>

// Problem constants (from reference)
#define NN   20000            // nodes
#define NE   320000           // edges (before self loops)
#define NE2  (NE + NN)        // edges incl. self loops
#define NG   64               // graphs
#define INF_ 6                // input features
#define EDF  2                // edge feature dim
#define NH   4                // heads
#define FD   64               // per-head dim
#define HF   256              // NH*FD
#define FCD  64               // pre-pool MLP dim
#define NCD  2                // classes

// bf16 helpers (RNE)
static __device__ __forceinline__ unsigned short f2bf(float f) {
  unsigned u = __float_as_uint(f);
  unsigned r = 0x7fffu + ((u >> 16) & 1u);
  return (unsigned short)((u + r) >> 16);
}
static __device__ __forceinline__ float4 bf2f4(uint2 p) {
  float4 v;
  v.x = __uint_as_float(p.x << 16);
  v.y = __uint_as_float(p.x & 0xffff0000u);
  v.z = __uint_as_float(p.y << 16);
  v.w = __uint_as_float(p.y & 0xffff0000u);
  return v;
}

// ---------------- CSR build ----------------

__global__ void k_count_sum(const int* __restrict__ ei, const float* __restrict__ ea,
                            int* __restrict__ cnt, float* __restrict__ la) {
  int e = blockIdx.x * blockDim.x + threadIdx.x;
  if (e >= NE) return;
  int d = ei[NE + e];                 // dst
  atomicAdd(&cnt[d], 1);
  atomicAdd(&la[2 * d],     ea[2 * e]);
  atomicAdd(&la[2 * d + 1], ea[2 * e + 1]);
}

// Single-block scan: rowptr = exclusive_scan(cnt); cursor = rowptr copy;
// also normalize self-loop attrs la /= max(cnt,1).
__global__ void k_scan(const int* __restrict__ cnt, float* __restrict__ la,
                       int* __restrict__ rowptr, int* __restrict__ cursor) {
  __shared__ int sc[1024];
  int t = threadIdx.x;
  const int CH = 20;                  // 1024*20 >= NN
  int base = t * CH;
  int s = 0;
  for (int i = base; i < base + CH && i < NN; ++i) s += cnt[i] + 1;
  sc[t] = s;
  __syncthreads();
  for (int o = 1; o < 1024; o <<= 1) {
    int add = (t >= o) ? sc[t - o] : 0;
    __syncthreads();
    sc[t] += add;
    __syncthreads();
  }
  int run = sc[t] - s;                // exclusive prefix
  for (int i = base; i < base + CH && i < NN; ++i) {
    rowptr[i] = run;
    cursor[i] = run;
    int c = cnt[i];
    run += c + 1;
    float inv = 1.0f / fmaxf((float)c, 1.0f);
    la[2 * i]     *= inv;
    la[2 * i + 1] *= inv;
  }
  if (t == 1023) rowptr[NN] = run;    // thread 1023's base >= NN, run == total
}

// Scatter edge records (src, a0, a1) into CSR order.
__global__ void k_scatter(const int* __restrict__ ei, const float* __restrict__ ea,
                          const float* __restrict__ la, int* __restrict__ cursor,
                          float4* __restrict__ rec) {
  int i = blockIdx.x * blockDim.x + threadIdx.x;
  if (i >= NE2) return;
  int s, d; float a0, a1;
  if (i < NE) {
    s = ei[i]; d = ei[NE + i]; a0 = ea[2 * i]; a1 = ea[2 * i + 1];
  } else {
    s = d = i - NE; a0 = la[2 * d]; a1 = la[2 * d + 1];
  }
  int pos = atomicAdd(&cursor[d], 1);
  rec[pos] = make_float4(__int_as_float(s), a0, a1, 0.0f);
}

// ---------------- layer-0 node transforms (K=6, trivial) ----------------

__global__ void k_l0_transform(const float* __restrict__ x,
                               const float* __restrict__ Wl, const float* __restrict__ bl,
                               const float* __restrict__ Wr, const float* __restrict__ br,
                               unsigned short* __restrict__ xlb, float* __restrict__ xr) {
  int n = blockIdx.x, c = threadIdx.x;
  float al = bl[c], ar = br[c];
#pragma unroll
  for (int k = 0; k < INF_; ++k) {
    float xv = x[n * INF_ + k];
    al = fmaf(xv, Wl[k * HF + c], al);
    ar = fmaf(xv, Wr[k * HF + c], ar);
  }
  xlb[(size_t)n * HF + c] = f2bf(al);
  xr[(size_t)n * HF + c] = ar;
}

// ---------------- layer-1 node transforms: x1(20000x256) @ {Wl1,Wr1}(256x256) ----------------
// 16 rows/block (grid 1250), thread = output col for BOTH Wl and Wr: 8 FMAs per
// LDS broadcast read -> VALU-bound instead of LDS-issue-bound; much bigger grid.

__global__ __launch_bounds__(256) void k_l1_transform(
    const float* __restrict__ x1,
    const float* __restrict__ Wl, const float* __restrict__ bl,
    const float* __restrict__ Wr, const float* __restrict__ br,
    unsigned short* __restrict__ xlb, float* __restrict__ xr) {
  __shared__ float xs[16 * HF];
  int c = threadIdx.x;
  int row0 = blockIdx.x * 16;
  const float4* s4 = (const float4*)(x1 + (size_t)row0 * HF);
  float4* d4 = (float4*)xs;
#pragma unroll
  for (int i = 0; i < 4; ++i) d4[i * 256 + c] = s4[i * 256 + c];
  __syncthreads();
  float accl[16], accr[16];
#pragma unroll
  for (int r = 0; r < 16; ++r) { accl[r] = 0.f; accr[r] = 0.f; }
  for (int k4 = 0; k4 < HF / 4; ++k4) {
    float wl[4], wr[4];
#pragma unroll
    for (int j = 0; j < 4; ++j) {
      wl[j] = Wl[(k4 * 4 + j) * HF + c];
      wr[j] = Wr[(k4 * 4 + j) * HF + c];
    }
#pragma unroll
    for (int r = 0; r < 16; ++r) {
      float4 xv = *(const float4*)&xs[r * HF + k4 * 4];
      accl[r] = fmaf(xv.x, wl[0], accl[r]);
      accl[r] = fmaf(xv.y, wl[1], accl[r]);
      accl[r] = fmaf(xv.z, wl[2], accl[r]);
      accl[r] = fmaf(xv.w, wl[3], accl[r]);
      accr[r] = fmaf(xv.x, wr[0], accr[r]);
      accr[r] = fmaf(xv.y, wr[1], accr[r]);
      accr[r] = fmaf(xv.z, wr[2], accr[r]);
      accr[r] = fmaf(xv.w, wr[3], accr[r]);
    }
  }
  float blv = bl[c], brv = br[c];
#pragma unroll
  for (int r = 0; r < 16; ++r) {
    xlb[(size_t)(row0 + r) * HF + c] = f2bf(accl[r] + blv);
    xr[(size_t)(row0 + r) * HF + c] = accr[r] + brv;
  }
}

// ---------------- fused GATv2: single-pass online-softmax, one WAVE per node ----------------
// xl gathered as bf16 (512 B/row): halves the L3 gather traffic that bounds this kernel.

template <bool L0>
__global__ __launch_bounds__(256) void k_agg(
    const unsigned short* __restrict__ xlb, const float* xr_,   // no restrict: x2out aliases
    const int* __restrict__ rowptr, const float4* __restrict__ rec,
    const float* __restrict__ att, const float* __restrict__ We,
    const float* __restrict__ bias,
    const float* __restrict__ x, const float* __restrict__ proj0,
    float* __restrict__ x1out,
    const float* __restrict__ x1in, float* x2out) {
  int wid = (blockIdx.x * 256 + threadIdx.x) >> 6;
  if (wid >= NN) return;
  int lane = threadIdx.x & 63;
  int n = wid;
  int cb = lane << 2;                    // channel base (0..252)

  float4 xr4 = *(const float4*)&xr_[(size_t)n * HF + cb];
  float4 at4 = *(const float4*)&att[cb];
  float4 w04 = *(const float4*)&We[cb];
  float4 w14 = *(const float4*)&We[HF + cb];

  int beg = rowptr[n];
  int deg = rowptr[n + 1] - beg;

  float mx = -3.4e38f, den = 0.f;
  float4 acc = make_float4(0.f, 0.f, 0.f, 0.f);

  for (int chunk = 0; chunk < deg; chunk += 64) {
    int m = min(64, deg - chunk);
    float4 r = make_float4(0.f, 0.f, 0.f, 0.f);
    if (lane < m) r = rec[beg + chunk + lane];
    int rs = __float_as_int(r.x);

    // prefetch edge 0
    int   sC  = __shfl(rs,  0, 64);
    float a0C = __shfl(r.y, 0, 64);
    float a1C = __shfl(r.z, 0, 64);
    uint2 pC = *(const uint2*)&xlb[(size_t)sC * HF + cb];

    for (int e = 0; e < m; ++e) {
      int sN = sC; float a0N = a0C, a1N = a1C;
      uint2 pN = pC;
      if (e + 1 < m) {
        sN  = __shfl(rs,  e + 1, 64);
        a0N = __shfl(r.y, e + 1, 64);
        a1N = __shfl(r.z, e + 1, 64);
        pN = *(const uint2*)&xlb[(size_t)sN * HF + cb];
      }
      float4 vC = bf2f4(pC);
      float4 mm;
      mm.x = vC.x + xr4.x + a0C * w04.x + a1C * w14.x;
      mm.y = vC.y + xr4.y + a0C * w04.y + a1C * w14.y;
      mm.z = vC.z + xr4.z + a0C * w04.z + a1C * w14.z;
      mm.w = vC.w + xr4.w + a0C * w04.w + a1C * w14.w;
      mm.x = (mm.x > 0.f) ? mm.x : 0.2f * mm.x;      // leaky_relu 0.2
      mm.y = (mm.y > 0.f) ? mm.y : 0.2f * mm.y;
      mm.z = (mm.z > 0.f) ? mm.z : 0.2f * mm.z;
      mm.w = (mm.w > 0.f) ? mm.w : 0.2f * mm.w;
      float t = mm.x * at4.x;
      t = fmaf(mm.y, at4.y, t);
      t = fmaf(mm.z, at4.z, t);
      t = fmaf(mm.w, at4.w, t);
      // per-head reduction over the 16-lane group
      t += __shfl_xor(t, 1, 64);
      t += __shfl_xor(t, 2, 64);
      t += __shfl_xor(t, 4, 64);
      t += __shfl_xor(t, 8, 64);
      // online softmax update
      float mn  = fmaxf(mx, t);
      float sc_ = __expf(mx - mn);     // exp(-inf)=0 handles first edge
      float w   = __expf(t - mn);
      den   = fmaf(den, sc_, w);
      acc.x = fmaf(acc.x, sc_, w * vC.x);
      acc.y = fmaf(acc.y, sc_, w * vC.y);
      acc.z = fmaf(acc.z, sc_, w * vC.z);
      acc.w = fmaf(acc.w, sc_, w * vC.w);
      mx = mn;
      pC = pN; a0C = a0N; a1C = a1N; sC = sN;
    }
  }

  float inv = 1.0f / den;
  float4 b4 = *(const float4*)&bias[cb];
  float4 o;
  o.x = fmaf(acc.x, inv, b4.x);
  o.y = fmaf(acc.y, inv, b4.y);
  o.z = fmaf(acc.z, inv, b4.z);
  o.w = fmaf(acc.w, inv, b4.w);
  o.x = (o.x > 0.f) ? o.x : expm1f(o.x);            // elu
  o.y = (o.y > 0.f) ? o.y : expm1f(o.y);
  o.z = (o.z > 0.f) ? o.z : expm1f(o.z);
  o.w = (o.w > 0.f) ? o.w : expm1f(o.w);

  if (L0) {
    float4 rr = make_float4(0.f, 0.f, 0.f, 0.f);
#pragma unroll
    for (int k = 0; k < INF_; ++k) {
      float xv = x[n * INF_ + k];                    // wave-uniform -> scalar load
      float4 p = *(const float4*)&proj0[k * HF + cb];
      rr.x = fmaf(xv, p.x, rr.x);
      rr.y = fmaf(xv, p.y, rr.y);
      rr.z = fmaf(xv, p.z, rr.z);
      rr.w = fmaf(xv, p.w, rr.w);
    }
    o.x += rr.x; o.y += rr.y; o.z += rr.z; o.w += rr.w;
    *(float4*)&x1out[(size_t)n * HF + cb] = o;
  } else {
    float4 x1v = *(const float4*)&x1in[(size_t)n * HF + cb];
    o.x += x1v.x; o.y += x1v.y; o.z += x1v.z; o.w += x1v.w;
    *(float4*)&x2out[(size_t)n * HF + cb] = o;       // aliases xr_ row n: safe (own row, after read)
  }
}

// ---------------- pre-pool MLP + graph pooling: z=elu(x2@Wp+bp); gpool += z ----------------

__global__ __launch_bounds__(256) void k_pool(
    const float* __restrict__ x2, const float* __restrict__ Wp,
    const float* __restrict__ bp, const int* __restrict__ batch,
    float* __restrict__ gpool) {
  __shared__ float xs[32 * HF];
  __shared__ int gid_s[32];
  int t = threadIdx.x;
  int row0 = blockIdx.x * 32;
  const float4* s4 = (const float4*)(x2 + (size_t)row0 * HF);
  float4* d4 = (float4*)xs;
#pragma unroll
  for (int i = 0; i < 8; ++i) d4[i * 256 + t] = s4[i * 256 + t];
  if (t < 32) gid_s[t] = batch[row0 + t];
  __syncthreads();
  int j = t & 63, rg = t >> 6;          // thread: col j, rows rg*8..rg*8+7
  float acc[8];
#pragma unroll
  for (int rr = 0; rr < 8; ++rr) acc[rr] = 0.f;
  for (int k4 = 0; k4 < HF / 4; ++k4) {
    float w0 = Wp[(k4 * 4 + 0) * FCD + j];
    float w1 = Wp[(k4 * 4 + 1) * FCD + j];
    float w2 = Wp[(k4 * 4 + 2) * FCD + j];
    float w3 = Wp[(k4 * 4 + 3) * FCD + j];
#pragma unroll
    for (int rr = 0; rr < 8; ++rr) {
      float4 xv = *(const float4*)&xs[(rg * 8 + rr) * HF + k4 * 4];
      acc[rr] = fmaf(xv.x, w0, acc[rr]);
      acc[rr] = fmaf(xv.y, w1, acc[rr]);
      acc[rr] = fmaf(xv.z, w2, acc[rr]);
      acc[rr] = fmaf(xv.w, w3, acc[rr]);
    }
  }
  float b = bp[j];
#pragma unroll
  for (int rr = 0; rr < 8; ++rr) {
    float a = acc[rr] + b;
    float z = (a > 0.f) ? a : expm1f(a);
    atomicAdd(&gpool[gid_s[rg * 8 + rr] * FCD + j], z);
  }
}

// ---------------- final classifier: out[g,k] = (gpool[g]/cnt[g]) @ Wc + bc ----------------
// count[g] via binary search on the SORTED batch array (no atomics needed).

__global__ void k_head(const float* __restrict__ gpool, const int* __restrict__ batch,
                       const float* __restrict__ Wc, const float* __restrict__ bc,
                       float* __restrict__ out) {
  int t = threadIdx.x;                 // 128 threads
  int g = t >> 1, k = t & 1;
  int lo = 0, hi = NN;
  while (lo < hi) { int mid = (lo + hi) >> 1; if (batch[mid] < g) lo = mid + 1; else hi = mid; }
  int c0 = lo;
  lo = 0; hi = NN;
  while (lo < hi) { int mid = (lo + hi) >> 1; if (batch[mid] < g + 1) lo = mid + 1; else hi = mid; }
  int c1 = lo;
  float inv = 1.0f / fmaxf((float)(c1 - c0), 1.0f);
  float a = bc[k];
  for (int j = 0; j < FCD; ++j)
    a = fmaf(gpool[g * FCD + j] * inv, Wc[j * NCD + k], a);
  out[g * NCD + k] = a;
}

// ---------------- launch ----------------

extern "C" void kernel_launch(void* const* d_in, const int* in_sizes, int n_in,
                              void* d_out, int out_size, void* d_ws, size_t ws_size,
                              hipStream_t stream) {
  const float* x    = (const float*)d_in[0];
  const int*   ei   = (const int*)d_in[1];    // [2,E] int
  const float* ea   = (const float*)d_in[2];  // [E,2]
  const int*   batch= (const int*)d_in[3];
  const float* Wl0  = (const float*)d_in[4];
  const float* bl0  = (const float*)d_in[5];
  const float* Wr0  = (const float*)d_in[6];
  const float* br0  = (const float*)d_in[7];
  const float* We0  = (const float*)d_in[8];
  const float* att0 = (const float*)d_in[9];
  const float* b0   = (const float*)d_in[10];
  const float* proj0= (const float*)d_in[11];
  const float* Wl1  = (const float*)d_in[12];
  const float* bl1  = (const float*)d_in[13];
  const float* Wr1  = (const float*)d_in[14];
  const float* br1  = (const float*)d_in[15];
  const float* We1  = (const float*)d_in[16];
  const float* att1 = (const float*)d_in[17];
  const float* b1   = (const float*)d_in[18];
  const float* Wp   = (const float*)d_in[19];
  const float* bp   = (const float*)d_in[20];
  const float* Wc   = (const float*)d_in[21];
  const float* bc   = (const float*)d_in[22];
  float* out = (float*)d_out;

  // workspace layout (all 16B aligned)
  char* ws = (char*)d_ws;
  size_t off = 0;
  int*   rowptr = (int*)(ws + off);   off += ((NN + 1) * 4 + 15) / 16 * 16;
  int*   cnt    = (int*)(ws + off);   off += (NN * 4 + 15) / 16 * 16;
  int*   cursor = (int*)(ws + off);   off += (NN * 4 + 15) / 16 * 16;
  float* la     = (float*)(ws + off); off += (NN * 2 * 4 + 15) / 16 * 16;
  float4* rec   = (float4*)(ws + off); off += (size_t)NE2 * 16;
  unsigned short* xlb = (unsigned short*)(ws + off); off += (size_t)NN * HF * 2;
  float* xr     = (float*)(ws + off); off += (size_t)NN * HF * 4;
  float* x1     = (float*)(ws + off); off += (size_t)NN * HF * 4;
  float* gpool  = (float*)(ws + off); off += NG * FCD * 4;
  float* x2     = xr;                  // alias: safe (each wave writes only its own row, after reading it)
  (void)ws_size; (void)in_sizes; (void)n_in; (void)out_size;

  // zero accumulators (ws is poisoned 0xAA before every call)
  hipMemsetAsync(cnt, 0, NN * 4, stream);
  hipMemsetAsync(la, 0, NN * 2 * 4, stream);
  hipMemsetAsync(gpool, 0, NG * FCD * 4, stream);

  // CSR build + self-loop mean attrs + edge records
  k_count_sum<<<(NE + 255) / 256, 256, 0, stream>>>(ei, ea, cnt, la);
  k_scan<<<1, 1024, 0, stream>>>(cnt, la, rowptr, cursor);
  k_scatter<<<(NE2 + 255) / 256, 256, 0, stream>>>(ei, ea, la, cursor, rec);

  // layer 0
  k_l0_transform<<<NN, 256, 0, stream>>>(x, Wl0, bl0, Wr0, br0, xlb, xr);
  k_agg<true><<<(NN * 64 + 255) / 256, 256, 0, stream>>>(
      xlb, xr, rowptr, rec, att0, We0, b0, x, proj0, x1, nullptr, nullptr);

  // layer 1
  k_l1_transform<<<NN / 16, 256, 0, stream>>>(x1, Wl1, bl1, Wr1, br1, xlb, xr);
  k_agg<false><<<(NN * 64 + 255) / 256, 256, 0, stream>>>(
      xlb, xr, rowptr, rec, att1, We1, b1, nullptr, nullptr, nullptr, x1, x2);

  // pre-pool MLP + pooling, then classifier
  k_pool<<<NN / 32, 256, 0, stream>>>(x2, Wp, bp, batch, gpool);
  k_head<<<1, 128, 0, stream>>>(gpool, batch, Wc, bc, out);
}

// Round 5
// 449.388 us; speedup vs baseline: 2.1054x; 1.0791x over previous
//
#include <hip/hip_runtime.h>
#include <math.h>

// Problem constants (from reference)
#define NN   20000            // nodes
#define NE   320000           // edges (before self loops)
#define NE2  (NE + NN)        // edges incl. self loops
#define NG   64               // graphs
#define INF_ 6                // input features
#define EDF  2                // edge feature dim
#define NH   4                // heads
#define FD   64               // per-head dim
#define HF   256              // NH*FD
#define FCD  64               // pre-pool MLP dim
#define NCD  2                // classes

typedef short bf16x8 __attribute__((ext_vector_type(8)));   // 8 bf16 (4 VGPRs)
typedef float f32x4  __attribute__((ext_vector_type(4)));   // MFMA acc

// bf16 helpers (RNE)
static __device__ __forceinline__ unsigned short f2bf(float f) {
  unsigned u = __float_as_uint(f);
  unsigned r = 0x7fffu + ((u >> 16) & 1u);
  return (unsigned short)((u + r) >> 16);
}
static __device__ __forceinline__ float4 bf2f4(uint2 p) {
  float4 v;
  v.x = __uint_as_float(p.x << 16);
  v.y = __uint_as_float(p.x & 0xffff0000u);
  v.z = __uint_as_float(p.y << 16);
  v.w = __uint_as_float(p.y & 0xffff0000u);
  return v;
}

// ---------------- CSR build ----------------

__global__ void k_count_sum(const int* __restrict__ ei, const float* __restrict__ ea,
                            int* __restrict__ cnt, float* __restrict__ la) {
  int e = blockIdx.x * blockDim.x + threadIdx.x;
  if (e >= NE) return;
  int d = ei[NE + e];                 // dst
  atomicAdd(&cnt[d], 1);
  atomicAdd(&la[2 * d],     ea[2 * e]);
  atomicAdd(&la[2 * d + 1], ea[2 * e + 1]);
}

// Single-block scan: rowptr = exclusive_scan(cnt); cursor = rowptr copy;
// also normalize self-loop attrs la /= max(cnt,1).
__global__ void k_scan(const int* __restrict__ cnt, float* __restrict__ la,
                       int* __restrict__ rowptr, int* __restrict__ cursor) {
  __shared__ int sc[1024];
  int t = threadIdx.x;
  const int CH = 20;                  // 1024*20 >= NN
  int base = t * CH;
  int s = 0;
  for (int i = base; i < base + CH && i < NN; ++i) s += cnt[i] + 1;
  sc[t] = s;
  __syncthreads();
  for (int o = 1; o < 1024; o <<= 1) {
    int add = (t >= o) ? sc[t - o] : 0;
    __syncthreads();
    sc[t] += add;
    __syncthreads();
  }
  int run = sc[t] - s;                // exclusive prefix
  for (int i = base; i < base + CH && i < NN; ++i) {
    rowptr[i] = run;
    cursor[i] = run;
    int c = cnt[i];
    run += c + 1;
    float inv = 1.0f / fmaxf((float)c, 1.0f);
    la[2 * i]     *= inv;
    la[2 * i + 1] *= inv;
  }
  if (t == 1023) rowptr[NN] = run;    // thread 1023's base >= NN, run == total
}

// Scatter edge records (src, a0, a1) into CSR order.
__global__ void k_scatter(const int* __restrict__ ei, const float* __restrict__ ea,
                          const float* __restrict__ la, int* __restrict__ cursor,
                          float4* __restrict__ rec) {
  int i = blockIdx.x * blockDim.x + threadIdx.x;
  if (i >= NE2) return;
  int s, d; float a0, a1;
  if (i < NE) {
    s = ei[i]; d = ei[NE + i]; a0 = ea[2 * i]; a1 = ea[2 * i + 1];
  } else {
    s = d = i - NE; a0 = la[2 * d]; a1 = la[2 * d + 1];
  }
  int pos = atomicAdd(&cursor[d], 1);
  rec[pos] = make_float4(__int_as_float(s), a0, a1, 0.0f);
}

// ---------------- weight convert+transpose: Wt[n][k] bf16, n<256: Wl1, n>=256: Wr1 ----------------

__global__ void k_wconv(const float* __restrict__ Wl, const float* __restrict__ Wr,
                        unsigned short* __restrict__ Wt) {
  int n = blockIdx.x;        // 0..511
  int k = threadIdx.x;       // 0..255
  const float* W = (n < 256) ? Wl : Wr;
  int nn = n & 255;
  Wt[n * 256 + k] = f2bf(W[k * 256 + nn]);
}

// ---------------- layer-0 node transforms (K=6, trivial) ----------------

__global__ void k_l0_transform(const float* __restrict__ x,
                               const float* __restrict__ Wl, const float* __restrict__ bl,
                               const float* __restrict__ Wr, const float* __restrict__ br,
                               unsigned short* __restrict__ xlb, float* __restrict__ xr) {
  int n = blockIdx.x, c = threadIdx.x;
  float al = bl[c], ar = br[c];
#pragma unroll
  for (int k = 0; k < INF_; ++k) {
    float xv = x[n * INF_ + k];
    al = fmaf(xv, Wl[k * HF + c], al);
    ar = fmaf(xv, Wr[k * HF + c], ar);
  }
  xlb[(size_t)n * HF + c] = f2bf(al);
  xr[(size_t)n * HF + c] = ar;
}

// ---------------- layer-1 transforms via MFMA: x1b @ Wt^T -> xlb (bf16) + xr (fp32) ----------------
// Block: 64 rows x 128 cols of the 512-wide concatenated [Wl|Wr] output.
// mfma_f32_16x16x32_bf16; A[m=lane&15][k=quad*8+j]; B[k=quad*8+j][n=lane&15];
// C/D: col=lane&15, row=quad*4+reg (m89/m91-verified).

__global__ __launch_bounds__(256) void k_l1_mfma(
    const unsigned short* __restrict__ x1b,   // [NN][256] bf16
    const unsigned short* __restrict__ Wt,    // [512][256] bf16
    const float* __restrict__ bl, const float* __restrict__ br,
    unsigned short* __restrict__ xlb, float* __restrict__ xr) {
  __shared__ unsigned short As[64][264];      // +8 pad: 2-way LDS aliasing only
  int t = threadIdx.x;
  int row0 = blockIdx.x * 64;
  {
    int r = t >> 2, seg = t & 3;              // 4 threads/row, 128 B each
    int grow = row0 + r; if (grow >= NN) grow = NN - 1;
    const uint4* src = (const uint4*)(x1b + (size_t)grow * HF + seg * 64);
    uint4* dst = (uint4*)&As[r][seg * 64];
#pragma unroll
    for (int i = 0; i < 8; ++i) dst[i] = src[i];
  }
  __syncthreads();

  int w = t >> 6, lane = t & 63;
  int quad = lane >> 4, ln = lane & 15;
  int n0 = blockIdx.y * 128;

  f32x4 acc[8];
#pragma unroll
  for (int i = 0; i < 8; ++i) acc[i] = (f32x4){0.f, 0.f, 0.f, 0.f};

  for (int kk = 0; kk < 256; kk += 32) {
    bf16x8 af = *(const bf16x8*)&As[w * 16 + ln][kk + quad * 8];
#pragma unroll
    for (int nt = 0; nt < 8; ++nt) {
      bf16x8 bfr = *(const bf16x8*)&Wt[(size_t)(n0 + nt * 16 + ln) * 256 + kk + quad * 8];
      acc[nt] = __builtin_amdgcn_mfma_f32_16x16x32_bf16(af, bfr, acc[nt], 0, 0, 0);
    }
  }

#pragma unroll
  for (int nt = 0; nt < 8; ++nt) {
    int gcol = n0 + nt * 16 + ln;
#pragma unroll
    for (int rg = 0; rg < 4; ++rg) {
      int grow = row0 + w * 16 + quad * 4 + rg;
      if (grow < NN) {
        float v = acc[nt][rg];
        if (gcol < HF) xlb[(size_t)grow * HF + gcol] = f2bf(v + bl[gcol]);
        else           xr[(size_t)grow * HF + (gcol - HF)] = v + br[gcol - HF];
      }
    }
  }
}

// ---------------- fused GATv2: single-pass online-softmax, one WAVE per node ----------------

template <bool L0>
__global__ __launch_bounds__(256) void k_agg(
    const unsigned short* __restrict__ xlb, const float* xr_,   // no restrict: x2out aliases
    const int* __restrict__ rowptr, const float4* __restrict__ rec,
    const float* __restrict__ att, const float* __restrict__ We,
    const float* __restrict__ bias,
    const float* __restrict__ x, const float* __restrict__ proj0,
    float* __restrict__ x1out, unsigned short* __restrict__ x1bout,
    const float* __restrict__ x1in, float* x2out) {
  int wid = (blockIdx.x * 256 + threadIdx.x) >> 6;
  if (wid >= NN) return;
  int lane = threadIdx.x & 63;
  int n = wid;
  int cb = lane << 2;                    // channel base (0..252)

  float4 xr4 = *(const float4*)&xr_[(size_t)n * HF + cb];
  float4 at4 = *(const float4*)&att[cb];
  float4 w04 = *(const float4*)&We[cb];
  float4 w14 = *(const float4*)&We[HF + cb];

  int beg = rowptr[n];
  int deg = rowptr[n + 1] - beg;

  float mx = -3.4e38f, den = 0.f;
  float4 acc = make_float4(0.f, 0.f, 0.f, 0.f);

  for (int chunk = 0; chunk < deg; chunk += 64) {
    int m = min(64, deg - chunk);
    float4 r = make_float4(0.f, 0.f, 0.f, 0.f);
    if (lane < m) r = rec[beg + chunk + lane];
    int rs = __float_as_int(r.x);

    // prefetch edge 0
    int   sC  = __shfl(rs,  0, 64);
    float a0C = __shfl(r.y, 0, 64);
    float a1C = __shfl(r.z, 0, 64);
    uint2 pC = *(const uint2*)&xlb[(size_t)sC * HF + cb];

    for (int e = 0; e < m; ++e) {
      int sN = sC; float a0N = a0C, a1N = a1C;
      uint2 pN = pC;
      if (e + 1 < m) {
        sN  = __shfl(rs,  e + 1, 64);
        a0N = __shfl(r.y, e + 1, 64);
        a1N = __shfl(r.z, e + 1, 64);
        pN = *(const uint2*)&xlb[(size_t)sN * HF + cb];
      }
      float4 vC = bf2f4(pC);
      float4 mm;
      mm.x = vC.x + xr4.x + a0C * w04.x + a1C * w14.x;
      mm.y = vC.y + xr4.y + a0C * w04.y + a1C * w14.y;
      mm.z = vC.z + xr4.z + a0C * w04.z + a1C * w14.z;
      mm.w = vC.w + xr4.w + a0C * w04.w + a1C * w14.w;
      mm.x = (mm.x > 0.f) ? mm.x : 0.2f * mm.x;      // leaky_relu 0.2
      mm.y = (mm.y > 0.f) ? mm.y : 0.2f * mm.y;
      mm.z = (mm.z > 0.f) ? mm.z : 0.2f * mm.z;
      mm.w = (mm.w > 0.f) ? mm.w : 0.2f * mm.w;
      float t = mm.x * at4.x;
      t = fmaf(mm.y, at4.y, t);
      t = fmaf(mm.z, at4.z, t);
      t = fmaf(mm.w, at4.w, t);
      // per-head reduction over the 16-lane group
      t += __shfl_xor(t, 1, 64);
      t += __shfl_xor(t, 2, 64);
      t += __shfl_xor(t, 4, 64);
      t += __shfl_xor(t, 8, 64);
      // online softmax update
      float mn  = fmaxf(mx, t);
      float sc_ = __expf(mx - mn);     // exp(-inf)=0 handles first edge
      float w   = __expf(t - mn);
      den   = fmaf(den, sc_, w);
      acc.x = fmaf(acc.x, sc_, w * vC.x);
      acc.y = fmaf(acc.y, sc_, w * vC.y);
      acc.z = fmaf(acc.z, sc_, w * vC.z);
      acc.w = fmaf(acc.w, sc_, w * vC.w);
      mx = mn;
      pC = pN; a0C = a0N; a1C = a1N; sC = sN;
    }
  }

  float inv = 1.0f / den;
  float4 b4 = *(const float4*)&bias[cb];
  float4 o;
  o.x = fmaf(acc.x, inv, b4.x);
  o.y = fmaf(acc.y, inv, b4.y);
  o.z = fmaf(acc.z, inv, b4.z);
  o.w = fmaf(acc.w, inv, b4.w);
  o.x = (o.x > 0.f) ? o.x : expm1f(o.x);            // elu
  o.y = (o.y > 0.f) ? o.y : expm1f(o.y);
  o.z = (o.z > 0.f) ? o.z : expm1f(o.z);
  o.w = (o.w > 0.f) ? o.w : expm1f(o.w);

  if (L0) {
    float4 rr = make_float4(0.f, 0.f, 0.f, 0.f);
#pragma unroll
    for (int k = 0; k < INF_; ++k) {
      float xv = x[n * INF_ + k];                    // wave-uniform -> scalar load
      float4 p = *(const float4*)&proj0[k * HF + cb];
      rr.x = fmaf(xv, p.x, rr.x);
      rr.y = fmaf(xv, p.y, rr.y);
      rr.z = fmaf(xv, p.z, rr.z);
      rr.w = fmaf(xv, p.w, rr.w);
    }
    o.x += rr.x; o.y += rr.y; o.z += rr.z; o.w += rr.w;
    *(float4*)&x1out[(size_t)n * HF + cb] = o;
    uint2 pk;                                        // bf16 copy feeds the MFMA transform
    pk.x = (unsigned)f2bf(o.x) | ((unsigned)f2bf(o.y) << 16);
    pk.y = (unsigned)f2bf(o.z) | ((unsigned)f2bf(o.w) << 16);
    *(uint2*)&x1bout[(size_t)n * HF + cb] = pk;
  } else {
    float4 x1v = *(const float4*)&x1in[(size_t)n * HF + cb];
    o.x += x1v.x; o.y += x1v.y; o.z += x1v.z; o.w += x1v.w;
    *(float4*)&x2out[(size_t)n * HF + cb] = o;       // aliases xr_ row n: safe (own row, after read)
  }
}

// ---------------- pre-pool MLP + graph pooling: z=elu(x2@Wp+bp); gpool += z ----------------

__global__ __launch_bounds__(256) void k_pool(
    const float* __restrict__ x2, const float* __restrict__ Wp,
    const float* __restrict__ bp, const int* __restrict__ batch,
    float* __restrict__ gpool) {
  __shared__ float xs[32 * HF];
  __shared__ int gid_s[32];
  int t = threadIdx.x;
  int row0 = blockIdx.x * 32;
  const float4* s4 = (const float4*)(x2 + (size_t)row0 * HF);
  float4* d4 = (float4*)xs;
#pragma unroll
  for (int i = 0; i < 8; ++i) d4[i * 256 + t] = s4[i * 256 + t];
  if (t < 32) gid_s[t] = batch[row0 + t];
  __syncthreads();
  int j = t & 63, rg = t >> 6;          // thread: col j, rows rg*8..rg*8+7
  float acc[8];
#pragma unroll
  for (int rr = 0; rr < 8; ++rr) acc[rr] = 0.f;
  for (int k4 = 0; k4 < HF / 4; ++k4) {
    float w0 = Wp[(k4 * 4 + 0) * FCD + j];
    float w1 = Wp[(k4 * 4 + 1) * FCD + j];
    float w2 = Wp[(k4 * 4 + 2) * FCD + j];
    float w3 = Wp[(k4 * 4 + 3) * FCD + j];
#pragma unroll
    for (int rr = 0; rr < 8; ++rr) {
      float4 xv = *(const float4*)&xs[(rg * 8 + rr) * HF + k4 * 4];
      acc[rr] = fmaf(xv.x, w0, acc[rr]);
      acc[rr] = fmaf(xv.y, w1, acc[rr]);
      acc[rr] = fmaf(xv.z, w2, acc[rr]);
      acc[rr] = fmaf(xv.w, w3, acc[rr]);
    }
  }
  float b = bp[j];
#pragma unroll
  for (int rr = 0; rr < 8; ++rr) {
    float a = acc[rr] + b;
    float z = (a > 0.f) ? a : expm1f(a);
    atomicAdd(&gpool[gid_s[rg * 8 + rr] * FCD + j], z);
  }
}

// ---------------- final classifier: out[g,k] = (gpool[g]/cnt[g]) @ Wc + bc ----------------

__global__ void k_head(const float* __restrict__ gpool, const int* __restrict__ batch,
                       const float* __restrict__ Wc, const float* __restrict__ bc,
                       float* __restrict__ out) {
  int t = threadIdx.x;                 // 128 threads
  int g = t >> 1, k = t & 1;
  int lo = 0, hi = NN;
  while (lo < hi) { int mid = (lo + hi) >> 1; if (batch[mid] < g) lo = mid + 1; else hi = mid; }
  int c0 = lo;
  lo = 0; hi = NN;
  while (lo < hi) { int mid = (lo + hi) >> 1; if (batch[mid] < g + 1) lo = mid + 1; else hi = mid; }
  int c1 = lo;
  float inv = 1.0f / fmaxf((float)(c1 - c0), 1.0f);
  float a = bc[k];
  for (int j = 0; j < FCD; ++j)
    a = fmaf(gpool[g * FCD + j] * inv, Wc[j * NCD + k], a);
  out[g * NCD + k] = a;
}

// ---------------- launch ----------------

extern "C" void kernel_launch(void* const* d_in, const int* in_sizes, int n_in,
                              void* d_out, int out_size, void* d_ws, size_t ws_size,
                              hipStream_t stream) {
  const float* x    = (const float*)d_in[0];
  const int*   ei   = (const int*)d_in[1];    // [2,E] int
  const float* ea   = (const float*)d_in[2];  // [E,2]
  const int*   batch= (const int*)d_in[3];
  const float* Wl0  = (const float*)d_in[4];
  const float* bl0  = (const float*)d_in[5];
  const float* Wr0  = (const float*)d_in[6];
  const float* br0  = (const float*)d_in[7];
  const float* We0  = (const float*)d_in[8];
  const float* att0 = (const float*)d_in[9];
  const float* b0   = (const float*)d_in[10];
  const float* proj0= (const float*)d_in[11];
  const float* Wl1  = (const float*)d_in[12];
  const float* bl1  = (const float*)d_in[13];
  const float* Wr1  = (const float*)d_in[14];
  const float* br1  = (const float*)d_in[15];
  const float* We1  = (const float*)d_in[16];
  const float* att1 = (const float*)d_in[17];
  const float* b1   = (const float*)d_in[18];
  const float* Wp   = (const float*)d_in[19];
  const float* bp   = (const float*)d_in[20];
  const float* Wc   = (const float*)d_in[21];
  const float* bc   = (const float*)d_in[22];
  float* out = (float*)d_out;

  // workspace layout (all 16B aligned)
  char* ws = (char*)d_ws;
  size_t off = 0;
  int*   rowptr = (int*)(ws + off);   off += ((NN + 1) * 4 + 15) / 16 * 16;
  int*   cnt    = (int*)(ws + off);   size_t cnt_off = off - (((NN + 1) * 4 + 15) / 16 * 16) + (((NN + 1) * 4 + 15) / 16 * 16); // = off
  off += (NN * 4 + 15) / 16 * 16;
  int*   cursor = (int*)(ws + off);   off += (NN * 4 + 15) / 16 * 16;
  float* la     = (float*)(ws + off); off += (NN * 2 * 4 + 15) / 16 * 16;
  float4* rec   = (float4*)(ws + off); off += (size_t)NE2 * 16;
  unsigned short* xlb = (unsigned short*)(ws + off); off += (size_t)NN * HF * 2;
  float* xr     = (float*)(ws + off); off += (size_t)NN * HF * 4;
  float* x1     = (float*)(ws + off); off += (size_t)NN * HF * 4;
  unsigned short* x1b = (unsigned short*)(ws + off); off += (size_t)NN * HF * 2;
  float* gpool  = (float*)(ws + off); off += NG * FCD * 4;
  float* x2     = xr;                  // alias: safe (each wave writes only its own row, after reading it)
  // Wt (512x256 bf16 = 256 KB) aliases cnt+cursor+la (320 KB): all dead after k_scatter,
  // and k_wconv runs after k_scatter.
  unsigned short* Wt = (unsigned short*)cnt;
  (void)ws_size; (void)in_sizes; (void)n_in; (void)out_size; (void)cnt_off;

  // zero accumulators (ws is poisoned 0xAA before every call)
  hipMemsetAsync(cnt, 0, NN * 4, stream);
  hipMemsetAsync(la, 0, NN * 2 * 4, stream);
  hipMemsetAsync(gpool, 0, NG * FCD * 4, stream);

  // CSR build + self-loop mean attrs + edge records
  k_count_sum<<<(NE + 255) / 256, 256, 0, stream>>>(ei, ea, cnt, la);
  k_scan<<<1, 1024, 0, stream>>>(cnt, la, rowptr, cursor);
  k_scatter<<<(NE2 + 255) / 256, 256, 0, stream>>>(ei, ea, la, cursor, rec);

  // weight convert (after scatter: Wt aliases cnt/cursor/la)
  k_wconv<<<512, 256, 0, stream>>>(Wl1, Wr1, Wt);

  // layer 0
  k_l0_transform<<<NN, 256, 0, stream>>>(x, Wl0, bl0, Wr0, br0, xlb, xr);
  k_agg<true><<<(NN * 64 + 255) / 256, 256, 0, stream>>>(
      xlb, xr, rowptr, rec, att0, We0, b0, x, proj0, x1, x1b, nullptr, nullptr);

  // layer 1 transforms via MFMA
  k_l1_mfma<<<dim3((NN + 63) / 64, 4), 256, 0, stream>>>(x1b, Wt, bl1, br1, xlb, xr);
  k_agg<false><<<(NN * 64 + 255) / 256, 256, 0, stream>>>(
      xlb, xr, rowptr, rec, att1, We1, b1, nullptr, nullptr, nullptr, nullptr, x1, x2);

  // pre-pool MLP + pooling, then classifier
  k_pool<<<NN / 32, 256, 0, stream>>>(x2, Wp, bp, batch, gpool);
  k_head<<<1, 128, 0, stream>>>(gpool, batch, Wc, bc, out);
}

// Round 6
// 377.342 us; speedup vs baseline: 2.5074x; 1.1909x over previous
//
#include <hip/hip_runtime.h>
#include <math.h>

// Problem constants (from reference)
#define NN   20000            // nodes
#define NE   320000           // edges (before self loops)
#define NE2  (NE + NN)        // edges incl. self loops
#define NG   64               // graphs
#define INF_ 6                // input features
#define EDF  2                // edge feature dim
#define NH   4                // heads
#define FD   64               // per-head dim
#define HF   256              // NH*FD
#define FCD  64               // pre-pool MLP dim
#define NCD  2                // classes
#define NBS  ((NN + 255) / 256)   // scan blocks = 79

typedef short bf16x8 __attribute__((ext_vector_type(8)));   // 8 bf16 (4 VGPRs)
typedef float f32x4  __attribute__((ext_vector_type(4)));   // MFMA acc

// bf16 helpers (RNE)
static __device__ __forceinline__ unsigned short f2bf(float f) {
  unsigned u = __float_as_uint(f);
  unsigned r = 0x7fffu + ((u >> 16) & 1u);
  return (unsigned short)((u + r) >> 16);
}
static __device__ __forceinline__ float4 bf2f4(uint2 p) {
  float4 v;
  v.x = __uint_as_float(p.x << 16);
  v.y = __uint_as_float(p.x & 0xffff0000u);
  v.z = __uint_as_float(p.y << 16);
  v.w = __uint_as_float(p.y & 0xffff0000u);
  return v;
}

// ---------------- CSR build ----------------

__global__ void k_count_sum(const int* __restrict__ ei, const float* __restrict__ ea,
                            int* __restrict__ cnt, float* __restrict__ la) {
  int e = blockIdx.x * blockDim.x + threadIdx.x;
  if (e >= NE) return;
  int d = ei[NE + e];                 // dst
  atomicAdd(&cnt[d], 1);
  atomicAdd(&la[2 * d],     ea[2 * e]);
  atomicAdd(&la[2 * d + 1], ea[2 * e + 1]);
}

// Parallel scan, 3 tiny kernels (replaces the 61us single-block k_scan).
__global__ void k_scan1(const int* __restrict__ cnt, int* __restrict__ bsum) {
  __shared__ int red[256];
  int b = blockIdx.x, t = threadIdx.x;
  int i = b * 256 + t;
  int v = (i < NN) ? cnt[i] + 1 : 0;
  red[t] = v;
  __syncthreads();
  for (int o = 128; o; o >>= 1) {
    if (t < o) red[t] += red[t + o];
    __syncthreads();
  }
  if (t == 0) bsum[b] = red[0];
}

__global__ void k_scan2(const int* __restrict__ bsum, int* __restrict__ boff) {
  __shared__ int s[128];
  int t = threadIdx.x;
  int v = (t < NBS) ? bsum[t] : 0;
  s[t] = v;
  __syncthreads();
  for (int o = 1; o < 128; o <<= 1) {
    int a = (t >= o) ? s[t - o] : 0;
    __syncthreads();
    s[t] += a;
    __syncthreads();
  }
  if (t < NBS) boff[t] = s[t] - v;    // exclusive
}

__global__ void k_scan3(const int* __restrict__ cnt, const int* __restrict__ boff,
                        int* __restrict__ rowptr, int* __restrict__ cursor,
                        float* __restrict__ la) {
  __shared__ int s[256];
  int b = blockIdx.x, t = threadIdx.x;
  int i = b * 256 + t;
  int c = (i < NN) ? cnt[i] + 1 : 0;
  s[t] = c;
  __syncthreads();
  for (int o = 1; o < 256; o <<= 1) {       // inclusive Hillis-Steele
    int a = (t >= o) ? s[t - o] : 0;
    __syncthreads();
    s[t] += a;
    __syncthreads();
  }
  if (i < NN) {
    int excl = boff[b] + s[t] - c;
    rowptr[i] = excl;
    cursor[i] = excl;
    float inv = 1.0f / fmaxf((float)(c - 1), 1.0f);
    la[2 * i]     *= inv;
    la[2 * i + 1] *= inv;
    if (i == NN - 1) rowptr[NN] = excl + c;
  }
}

// Scatter edge records (src, a0, a1) into CSR order.
__global__ void k_scatter(const int* __restrict__ ei, const float* __restrict__ ea,
                          const float* __restrict__ la, int* __restrict__ cursor,
                          float4* __restrict__ rec) {
  int i = blockIdx.x * blockDim.x + threadIdx.x;
  if (i >= NE2) return;
  int s, d; float a0, a1;
  if (i < NE) {
    s = ei[i]; d = ei[NE + i]; a0 = ea[2 * i]; a1 = ea[2 * i + 1];
  } else {
    s = d = i - NE; a0 = la[2 * d]; a1 = la[2 * d + 1];
  }
  int pos = atomicAdd(&cursor[d], 1);
  rec[pos] = make_float4(__int_as_float(s), a0, a1, 0.0f);
}

// ---------------- weight convert into B-fragment-swizzled order ----------------
// Wsw[((ntg*8 + kk8)*64 + lane)*8 + j] = W[k][n], n = ntg*16+(lane&15),
// k = kk8*32+(lane>>4)*8+j.  ntg<16 -> Wl1 cols, ntg>=16 -> Wr1 cols.
// Makes every B-fragment load in k_l1_mfma one fully-coalesced 1KB wave read.

__global__ void k_wconv(const float* __restrict__ Wl, const float* __restrict__ Wr,
                        unsigned short* __restrict__ Wsw) {
  int id = blockIdx.x * 256 + threadIdx.x;      // 0..131071
  int j = id & 7, lane = (id >> 3) & 63, kk8 = (id >> 9) & 7, ntg = id >> 12;
  int n = ntg * 16 + (lane & 15);
  int k = kk8 * 32 + (lane >> 4) * 8 + j;
  float v = (n < 256) ? Wl[k * 256 + n] : Wr[k * 256 + (n - 256)];
  Wsw[id] = f2bf(v);
}

// ---------------- layer-0 node transforms (K=6, trivial) ----------------

__global__ void k_l0_transform(const float* __restrict__ x,
                               const float* __restrict__ Wl, const float* __restrict__ bl,
                               const float* __restrict__ Wr, const float* __restrict__ br,
                               unsigned short* __restrict__ xlb, float* __restrict__ xr) {
  int n = blockIdx.x, c = threadIdx.x;
  float al = bl[c], ar = br[c];
#pragma unroll
  for (int k = 0; k < INF_; ++k) {
    float xv = x[n * INF_ + k];
    al = fmaf(xv, Wl[k * HF + c], al);
    ar = fmaf(xv, Wr[k * HF + c], ar);
  }
  xlb[(size_t)n * HF + c] = f2bf(al);
  xr[(size_t)n * HF + c] = ar;
}

// ---------------- layer-1 transforms via MFMA ----------------
// Block: 64 rows x 128 cols of the 512-wide [Wl|Wr] output. y<2 -> xlb (bf16),
// y>=2 -> xr (fp32). A staged in LDS (coalesced in, conflict-free out);
// B from swizzled Wsw (coalesced); output staged in LDS then coalesced stores.

__global__ __launch_bounds__(256) void k_l1_mfma(
    const unsigned short* __restrict__ x1b,   // [NN][256] bf16
    const unsigned short* __restrict__ Wsw,   // swizzled, 256 KB
    const float* __restrict__ bl, const float* __restrict__ br,
    unsigned short* __restrict__ xlb, float* __restrict__ xr) {
  __shared__ union {
    unsigned short a[64][264];                // 33792 B
    float o[64][132];                         // 33792 B
  } sm;
  int t = threadIdx.x;
  int row0 = blockIdx.x * 64;
  // stage A: lane i copies bytes idx*16 -> fully coalesced global reads
#pragma unroll
  for (int it = 0; it < 8; ++it) {
    int idx = it * 256 + t;
    int row = idx >> 5, c16 = idx & 31;
    int grow = row0 + row; if (grow >= NN) grow = NN - 1;
    *(uint4*)&sm.a[row][c16 * 8] = *(const uint4*)(x1b + (size_t)grow * HF + c16 * 8);
  }
  __syncthreads();

  int w = t >> 6, lane = t & 63;
  int quad = lane >> 4, ln = lane & 15;
  int y = blockIdx.y;                         // 0..3

  f32x4 acc[8];
#pragma unroll
  for (int i = 0; i < 8; ++i) acc[i] = (f32x4){0.f, 0.f, 0.f, 0.f};

  for (int kk8 = 0; kk8 < 8; ++kk8) {
    bf16x8 af = *(const bf16x8*)&sm.a[w * 16 + ln][kk8 * 32 + quad * 8];
#pragma unroll
    for (int nt = 0; nt < 8; ++nt) {
      bf16x8 bfr = *(const bf16x8*)&Wsw[(size_t)((((y * 8 + nt) * 8 + kk8) * 64) + lane) * 8];
      acc[nt] = __builtin_amdgcn_mfma_f32_16x16x32_bf16(af, bfr, acc[nt], 0, 0, 0);
    }
  }
  __syncthreads();                            // done with sm.a
  // scatter acc into LDS output tile (C/D: col=ln, row=quad*4+rg)
#pragma unroll
  for (int nt = 0; nt < 8; ++nt)
#pragma unroll
    for (int rg = 0; rg < 4; ++rg)
      sm.o[w * 16 + quad * 4 + rg][nt * 16 + ln] = acc[nt][rg];
  __syncthreads();

  if (y < 2) {                                // bf16 -> xlb, cols y*128..+127
    int cb8 = (t & 15) * 8;
    int rsub = t >> 4;                        // 0..15
    int gcol = y * 128 + cb8;
    float4 b0 = *(const float4*)&bl[gcol];
    float4 b1 = *(const float4*)&bl[gcol + 4];
#pragma unroll
    for (int i = 0; i < 4; ++i) {
      int row = i * 16 + rsub;
      int grow = row0 + row;
      if (grow < NN) {
        unsigned h0 = f2bf(sm.o[row][cb8 + 0] + b0.x);
        unsigned h1 = f2bf(sm.o[row][cb8 + 1] + b0.y);
        unsigned h2 = f2bf(sm.o[row][cb8 + 2] + b0.z);
        unsigned h3 = f2bf(sm.o[row][cb8 + 3] + b0.w);
        unsigned h4 = f2bf(sm.o[row][cb8 + 4] + b1.x);
        unsigned h5 = f2bf(sm.o[row][cb8 + 5] + b1.y);
        unsigned h6 = f2bf(sm.o[row][cb8 + 6] + b1.z);
        unsigned h7 = f2bf(sm.o[row][cb8 + 7] + b1.w);
        uint4 pk;
        pk.x = h0 | (h1 << 16);
        pk.y = h2 | (h3 << 16);
        pk.z = h4 | (h5 << 16);
        pk.w = h6 | (h7 << 16);
        *(uint4*)&xlb[(size_t)grow * HF + gcol] = pk;
      }
    }
  } else {                                    // fp32 -> xr, cols (y-2)*128..+127
    int cb4 = (t & 31) * 4;
    int rsub = t >> 5;                        // 0..7
    int gcol = (y - 2) * 128 + cb4;
    float4 b4 = *(const float4*)&br[gcol];
#pragma unroll
    for (int i = 0; i < 8; ++i) {
      int row = i * 8 + rsub;
      int grow = row0 + row;
      if (grow < NN) {
        float4 v;
        v.x = sm.o[row][cb4 + 0] + b4.x;
        v.y = sm.o[row][cb4 + 1] + b4.y;
        v.z = sm.o[row][cb4 + 2] + b4.z;
        v.w = sm.o[row][cb4 + 3] + b4.w;
        *(float4*)&xr[(size_t)grow * HF + gcol] = v;
      }
    }
  }
}

// ---------------- fused GATv2: single-pass online-softmax, one WAVE per node ----------------

template <bool L0>
__global__ __launch_bounds__(256) void k_agg(
    const unsigned short* __restrict__ xlb, const float* xr_,   // no restrict: x2out aliases
    const int* __restrict__ rowptr, const float4* __restrict__ rec,
    const float* __restrict__ att, const float* __restrict__ We,
    const float* __restrict__ bias,
    const float* __restrict__ x, const float* __restrict__ proj0,
    float* __restrict__ x1out, unsigned short* __restrict__ x1bout,
    const float* __restrict__ x1in, float* x2out) {
  int wid = (blockIdx.x * 256 + threadIdx.x) >> 6;
  if (wid >= NN) return;
  int lane = threadIdx.x & 63;
  int n = wid;
  int cb = lane << 2;                    // channel base (0..252)

  float4 xr4 = *(const float4*)&xr_[(size_t)n * HF + cb];
  float4 at4 = *(const float4*)&att[cb];
  float4 w04 = *(const float4*)&We[cb];
  float4 w14 = *(const float4*)&We[HF + cb];

  int beg = rowptr[n];
  int deg = rowptr[n + 1] - beg;

  float mx = -3.4e38f, den = 0.f;
  float4 acc = make_float4(0.f, 0.f, 0.f, 0.f);

  for (int chunk = 0; chunk < deg; chunk += 64) {
    int m = min(64, deg - chunk);
    float4 r = make_float4(0.f, 0.f, 0.f, 0.f);
    if (lane < m) r = rec[beg + chunk + lane];
    int rs = __float_as_int(r.x);

    // prefetch edge 0
    int   sC  = __shfl(rs,  0, 64);
    float a0C = __shfl(r.y, 0, 64);
    float a1C = __shfl(r.z, 0, 64);
    uint2 pC = *(const uint2*)&xlb[(size_t)sC * HF + cb];

    for (int e = 0; e < m; ++e) {
      int sN = sC; float a0N = a0C, a1N = a1C;
      uint2 pN = pC;
      if (e + 1 < m) {
        sN  = __shfl(rs,  e + 1, 64);
        a0N = __shfl(r.y, e + 1, 64);
        a1N = __shfl(r.z, e + 1, 64);
        pN = *(const uint2*)&xlb[(size_t)sN * HF + cb];
      }
      float4 vC = bf2f4(pC);
      float4 mm;
      mm.x = vC.x + xr4.x + a0C * w04.x + a1C * w14.x;
      mm.y = vC.y + xr4.y + a0C * w04.y + a1C * w14.y;
      mm.z = vC.z + xr4.z + a0C * w04.z + a1C * w14.z;
      mm.w = vC.w + xr4.w + a0C * w04.w + a1C * w14.w;
      mm.x = (mm.x > 0.f) ? mm.x : 0.2f * mm.x;      // leaky_relu 0.2
      mm.y = (mm.y > 0.f) ? mm.y : 0.2f * mm.y;
      mm.z = (mm.z > 0.f) ? mm.z : 0.2f * mm.z;
      mm.w = (mm.w > 0.f) ? mm.w : 0.2f * mm.w;
      float t = mm.x * at4.x;
      t = fmaf(mm.y, at4.y, t);
      t = fmaf(mm.z, at4.z, t);
      t = fmaf(mm.w, at4.w, t);
      // per-head reduction over the 16-lane group
      t += __shfl_xor(t, 1, 64);
      t += __shfl_xor(t, 2, 64);
      t += __shfl_xor(t, 4, 64);
      t += __shfl_xor(t, 8, 64);
      // online softmax update
      float mn  = fmaxf(mx, t);
      float sc_ = __expf(mx - mn);     // exp(-inf)=0 handles first edge
      float w   = __expf(t - mn);
      den   = fmaf(den, sc_, w);
      acc.x = fmaf(acc.x, sc_, w * vC.x);
      acc.y = fmaf(acc.y, sc_, w * vC.y);
      acc.z = fmaf(acc.z, sc_, w * vC.z);
      acc.w = fmaf(acc.w, sc_, w * vC.w);
      mx = mn;
      pC = pN; a0C = a0N; a1C = a1N; sC = sN;
    }
  }

  float inv = 1.0f / den;
  float4 b4 = *(const float4*)&bias[cb];
  float4 o;
  o.x = fmaf(acc.x, inv, b4.x);
  o.y = fmaf(acc.y, inv, b4.y);
  o.z = fmaf(acc.z, inv, b4.z);
  o.w = fmaf(acc.w, inv, b4.w);
  o.x = (o.x > 0.f) ? o.x : expm1f(o.x);            // elu
  o.y = (o.y > 0.f) ? o.y : expm1f(o.y);
  o.z = (o.z > 0.f) ? o.z : expm1f(o.z);
  o.w = (o.w > 0.f) ? o.w : expm1f(o.w);

  if (L0) {
    float4 rr = make_float4(0.f, 0.f, 0.f, 0.f);
#pragma unroll
    for (int k = 0; k < INF_; ++k) {
      float xv = x[n * INF_ + k];                    // wave-uniform -> scalar load
      float4 p = *(const float4*)&proj0[k * HF + cb];
      rr.x = fmaf(xv, p.x, rr.x);
      rr.y = fmaf(xv, p.y, rr.y);
      rr.z = fmaf(xv, p.z, rr.z);
      rr.w = fmaf(xv, p.w, rr.w);
    }
    o.x += rr.x; o.y += rr.y; o.z += rr.z; o.w += rr.w;
    *(float4*)&x1out[(size_t)n * HF + cb] = o;
    uint2 pk;                                        // bf16 copy feeds the MFMA transform
    pk.x = (unsigned)f2bf(o.x) | ((unsigned)f2bf(o.y) << 16);
    pk.y = (unsigned)f2bf(o.z) | ((unsigned)f2bf(o.w) << 16);
    *(uint2*)&x1bout[(size_t)n * HF + cb] = pk;
  } else {
    float4 x1v = *(const float4*)&x1in[(size_t)n * HF + cb];
    o.x += x1v.x; o.y += x1v.y; o.z += x1v.z; o.w += x1v.w;
    *(float4*)&x2out[(size_t)n * HF + cb] = o;       // aliases xr_ row n: safe (own row, after read)
  }
}

// ---------------- pre-pool MLP + graph pooling: z=elu(x2@Wp+bp); gpool += z ----------------

__global__ __launch_bounds__(256) void k_pool(
    const float* __restrict__ x2, const float* __restrict__ Wp,
    const float* __restrict__ bp, const int* __restrict__ batch,
    float* __restrict__ gpool) {
  __shared__ float xs[32 * HF];
  __shared__ int gid_s[32];
  int t = threadIdx.x;
  int row0 = blockIdx.x * 32;
  const float4* s4 = (const float4*)(x2 + (size_t)row0 * HF);
  float4* d4 = (float4*)xs;
#pragma unroll
  for (int i = 0; i < 8; ++i) d4[i * 256 + t] = s4[i * 256 + t];
  if (t < 32) gid_s[t] = batch[row0 + t];
  __syncthreads();
  int j = t & 63, rg = t >> 6;          // thread: col j, rows rg*8..rg*8+7
  float acc[8];
#pragma unroll
  for (int rr = 0; rr < 8; ++rr) acc[rr] = 0.f;
  for (int k4 = 0; k4 < HF / 4; ++k4) {
    float w0 = Wp[(k4 * 4 + 0) * FCD + j];
    float w1 = Wp[(k4 * 4 + 1) * FCD + j];
    float w2 = Wp[(k4 * 4 + 2) * FCD + j];
    float w3 = Wp[(k4 * 4 + 3) * FCD + j];
#pragma unroll
    for (int rr = 0; rr < 8; ++rr) {
      float4 xv = *(const float4*)&xs[(rg * 8 + rr) * HF + k4 * 4];
      acc[rr] = fmaf(xv.x, w0, acc[rr]);
      acc[rr] = fmaf(xv.y, w1, acc[rr]);
      acc[rr] = fmaf(xv.z, w2, acc[rr]);
      acc[rr] = fmaf(xv.w, w3, acc[rr]);
    }
  }
  float b = bp[j];
#pragma unroll
  for (int rr = 0; rr < 8; ++rr) {
    float a = acc[rr] + b;
    float z = (a > 0.f) ? a : expm1f(a);
    atomicAdd(&gpool[gid_s[rg * 8 + rr] * FCD + j], z);
  }
}

// ---------------- final classifier: out[g,k] = (gpool[g]/cnt[g]) @ Wc + bc ----------------

__global__ void k_head(const float* __restrict__ gpool, const int* __restrict__ batch,
                       const float* __restrict__ Wc, const float* __restrict__ bc,
                       float* __restrict__ out) {
  int t = threadIdx.x;                 // 128 threads
  int g = t >> 1, k = t & 1;
  int lo = 0, hi = NN;
  while (lo < hi) { int mid = (lo + hi) >> 1; if (batch[mid] < g) lo = mid + 1; else hi = mid; }
  int c0 = lo;
  lo = 0; hi = NN;
  while (lo < hi) { int mid = (lo + hi) >> 1; if (batch[mid] < g + 1) lo = mid + 1; else hi = mid; }
  int c1 = lo;
  float inv = 1.0f / fmaxf((float)(c1 - c0), 1.0f);
  float a = bc[k];
  for (int j = 0; j < FCD; ++j)
    a = fmaf(gpool[g * FCD + j] * inv, Wc[j * NCD + k], a);
  out[g * NCD + k] = a;
}

// ---------------- launch ----------------

extern "C" void kernel_launch(void* const* d_in, const int* in_sizes, int n_in,
                              void* d_out, int out_size, void* d_ws, size_t ws_size,
                              hipStream_t stream) {
  const float* x    = (const float*)d_in[0];
  const int*   ei   = (const int*)d_in[1];    // [2,E] int
  const float* ea   = (const float*)d_in[2];  // [E,2]
  const int*   batch= (const int*)d_in[3];
  const float* Wl0  = (const float*)d_in[4];
  const float* bl0  = (const float*)d_in[5];
  const float* Wr0  = (const float*)d_in[6];
  const float* br0  = (const float*)d_in[7];
  const float* We0  = (const float*)d_in[8];
  const float* att0 = (const float*)d_in[9];
  const float* b0   = (const float*)d_in[10];
  const float* proj0= (const float*)d_in[11];
  const float* Wl1  = (const float*)d_in[12];
  const float* bl1  = (const float*)d_in[13];
  const float* Wr1  = (const float*)d_in[14];
  const float* br1  = (const float*)d_in[15];
  const float* We1  = (const float*)d_in[16];
  const float* att1 = (const float*)d_in[17];
  const float* b1   = (const float*)d_in[18];
  const float* Wp   = (const float*)d_in[19];
  const float* bp   = (const float*)d_in[20];
  const float* Wc   = (const float*)d_in[21];
  const float* bc   = (const float*)d_in[22];
  float* out = (float*)d_out;

  // workspace layout (all 16B aligned)
  char* ws = (char*)d_ws;
  size_t off = 0;
  int*   rowptr = (int*)(ws + off);   off += ((NN + 1) * 4 + 15) / 16 * 16;
  int*   cnt    = (int*)(ws + off);   off += (NN * 4 + 15) / 16 * 16;
  int*   cursor = (int*)(ws + off);   off += (NN * 4 + 15) / 16 * 16;
  float* la     = (float*)(ws + off); off += (NN * 2 * 4 + 15) / 16 * 16;
  float4* rec   = (float4*)(ws + off); off += (size_t)NE2 * 16;
  unsigned short* xlb = (unsigned short*)(ws + off); off += (size_t)NN * HF * 2;
  float* xr     = (float*)(ws + off); off += (size_t)NN * HF * 4;
  float* x1     = (float*)(ws + off); off += (size_t)NN * HF * 4;
  unsigned short* x1b = (unsigned short*)(ws + off); off += (size_t)NN * HF * 2;
  float* gpool  = (float*)(ws + off); off += NG * FCD * 4;
  int*   bsum   = (int*)(ws + off);   off += (NBS * 4 + 15) / 16 * 16;
  int*   boff   = (int*)(ws + off);   off += (NBS * 4 + 15) / 16 * 16;
  float* x2     = xr;                  // alias: safe (each wave writes only its own row, after reading it)
  // Wsw (256 KB) aliases cnt+cursor+la (320 KB): all dead after k_scatter.
  unsigned short* Wsw = (unsigned short*)cnt;
  (void)ws_size; (void)in_sizes; (void)n_in; (void)out_size;

  // zero accumulators (ws is poisoned 0xAA before every call)
  hipMemsetAsync(cnt, 0, NN * 4, stream);
  hipMemsetAsync(la, 0, NN * 2 * 4, stream);
  hipMemsetAsync(gpool, 0, NG * FCD * 4, stream);

  // CSR build + self-loop mean attrs + edge records
  k_count_sum<<<(NE + 255) / 256, 256, 0, stream>>>(ei, ea, cnt, la);
  k_scan1<<<NBS, 256, 0, stream>>>(cnt, bsum);
  k_scan2<<<1, 128, 0, stream>>>(bsum, boff);
  k_scan3<<<NBS, 256, 0, stream>>>(cnt, boff, rowptr, cursor, la);
  k_scatter<<<(NE2 + 255) / 256, 256, 0, stream>>>(ei, ea, la, cursor, rec);

  // weight convert (after scatter: Wsw aliases cnt/cursor/la)
  k_wconv<<<512, 256, 0, stream>>>(Wl1, Wr1, Wsw);

  // layer 0
  k_l0_transform<<<NN, 256, 0, stream>>>(x, Wl0, bl0, Wr0, br0, xlb, xr);
  k_agg<true><<<(NN * 64 + 255) / 256, 256, 0, stream>>>(
      xlb, xr, rowptr, rec, att0, We0, b0, x, proj0, x1, x1b, nullptr, nullptr);

  // layer 1 transforms via MFMA
  k_l1_mfma<<<dim3((NN + 63) / 64, 4), 256, 0, stream>>>(x1b, Wsw, bl1, br1, xlb, xr);
  k_agg<false><<<(NN * 64 + 255) / 256, 256, 0, stream>>>(
      xlb, xr, rowptr, rec, att1, We1, b1, nullptr, nullptr, nullptr, nullptr, x1, x2);

  // pre-pool MLP + pooling, then classifier
  k_pool<<<NN / 32, 256, 0, stream>>>(x2, Wp, bp, batch, gpool);
  k_head<<<1, 128, 0, stream>>>(gpool, batch, Wc, bc, out);
}

// Round 7
// 319.803 us; speedup vs baseline: 2.9585x; 1.1799x over previous
//
#include <hip/hip_runtime.h>
#include <math.h>

// Problem constants (from reference)
#define NN   20000            // nodes
#define NE   320000           // edges (before self loops)
#define NE2  (NE + NN)        // edges incl. self loops
#define NG   64               // graphs
#define INF_ 6                // input features
#define EDF  2                // edge feature dim
#define NH   4                // heads
#define FD   64               // per-head dim
#define HF   256              // NH*FD
#define FCD  64               // pre-pool MLP dim
#define NCD  2                // classes
#define NBS  ((NN + 255) / 256)   // scan blocks = 79

typedef short bf16x8 __attribute__((ext_vector_type(8)));   // 8 bf16 (4 VGPRs)
typedef float f32x4  __attribute__((ext_vector_type(4)));   // MFMA acc

// bf16 helpers (RNE)
static __device__ __forceinline__ unsigned short f2bf(float f) {
  unsigned u = __float_as_uint(f);
  unsigned r = 0x7fffu + ((u >> 16) & 1u);
  return (unsigned short)((u + r) >> 16);
}
static __device__ __forceinline__ float4 bf2f4(uint2 p) {
  float4 v;
  v.x = __uint_as_float(p.x << 16);
  v.y = __uint_as_float(p.x & 0xffff0000u);
  v.z = __uint_as_float(p.y << 16);
  v.w = __uint_as_float(p.y & 0xffff0000u);
  return v;
}

// ---------------- CSR build ----------------

// 1 atomic per edge (la accumulation moved to atomic-free k_selfloop).
__global__ void k_count(const int* __restrict__ ei, int* __restrict__ cnt) {
  int e = blockIdx.x * blockDim.x + threadIdx.x;
  if (e >= NE) return;
  atomicAdd(&cnt[ei[NE + e]], 1);
}

// Parallel scan, 3 tiny kernels.
__global__ void k_scan1(const int* __restrict__ cnt, int* __restrict__ bsum) {
  __shared__ int red[256];
  int b = blockIdx.x, t = threadIdx.x;
  int i = b * 256 + t;
  int v = (i < NN) ? cnt[i] + 1 : 0;
  red[t] = v;
  __syncthreads();
  for (int o = 128; o; o >>= 1) {
    if (t < o) red[t] += red[t + o];
    __syncthreads();
  }
  if (t == 0) bsum[b] = red[0];
}

__global__ void k_scan2(const int* __restrict__ bsum, int* __restrict__ boff) {
  __shared__ int s[128];
  int t = threadIdx.x;
  int v = (t < NBS) ? bsum[t] : 0;
  s[t] = v;
  __syncthreads();
  for (int o = 1; o < 128; o <<= 1) {
    int a = (t >= o) ? s[t - o] : 0;
    __syncthreads();
    s[t] += a;
    __syncthreads();
  }
  if (t < NBS) boff[t] = s[t] - v;    // exclusive
}

__global__ void k_scan3(const int* __restrict__ cnt, const int* __restrict__ boff,
                        int* __restrict__ rowptr, int* __restrict__ cursor) {
  __shared__ int s[256];
  int b = blockIdx.x, t = threadIdx.x;
  int i = b * 256 + t;
  int c = (i < NN) ? cnt[i] + 1 : 0;
  s[t] = c;
  __syncthreads();
  for (int o = 1; o < 256; o <<= 1) {       // inclusive Hillis-Steele
    int a = (t >= o) ? s[t - o] : 0;
    __syncthreads();
    s[t] += a;
    __syncthreads();
  }
  if (i < NN) {
    int excl = boff[b] + s[t] - c;
    rowptr[i] = excl;
    cursor[i] = excl;
    if (i == NN - 1) rowptr[NN] = excl + c;
  }
}

// Scatter real-edge records (src, a0, a1) into CSR order (last slot per node
// is reserved for the self-loop, filled by k_selfloop).
__global__ void k_scatter(const int* __restrict__ ei, const float* __restrict__ ea,
                          int* __restrict__ cursor, float4* __restrict__ rec) {
  int i = blockIdx.x * blockDim.x + threadIdx.x;
  if (i >= NE) return;
  int s = ei[i], d = ei[NE + i];
  int pos = atomicAdd(&cursor[d], 1);
  rec[pos] = make_float4(__int_as_float(s), ea[2 * i], ea[2 * i + 1], 0.0f);
}

// Self-loop record = (n, mean of incoming attrs). Wave per node, no atomics.
__global__ __launch_bounds__(256) void k_selfloop(const int* __restrict__ rowptr,
                                                  float4* __restrict__ rec) {
  int wid = (blockIdx.x * 256 + threadIdx.x) >> 6;
  if (wid >= NN) return;
  int lane = threadIdx.x & 63;
  int beg = rowptr[wid], slot = rowptr[wid + 1] - 1;   // [beg,slot) real edges
  int cnt = slot - beg;
  float a0 = 0.f, a1 = 0.f;
  for (int i = beg + lane; i < slot; i += 64) {
    float4 r = rec[i];
    a0 += r.y; a1 += r.z;
  }
#pragma unroll
  for (int o = 32; o; o >>= 1) {
    a0 += __shfl_xor(a0, o, 64);
    a1 += __shfl_xor(a1, o, 64);
  }
  if (lane == 0) {
    float inv = 1.0f / fmaxf((float)cnt, 1.0f);
    rec[slot] = make_float4(__int_as_float(wid), a0 * inv, a1 * inv, 0.0f);
  }
}

// ---------------- weight convert into B-fragment-swizzled order ----------------

__global__ void k_wconv(const float* __restrict__ Wl, const float* __restrict__ Wr,
                        unsigned short* __restrict__ Wsw) {
  int id = blockIdx.x * 256 + threadIdx.x;      // 0..131071
  int j = id & 7, lane = (id >> 3) & 63, kk8 = (id >> 9) & 7, ntg = id >> 12;
  int n = ntg * 16 + (lane & 15);
  int k = kk8 * 32 + (lane >> 4) * 8 + j;
  float v = (n < 256) ? Wl[k * 256 + n] : Wr[k * 256 + (n - 256)];
  Wsw[id] = f2bf(v);
}

// ---------------- layer-0 node transforms (K=6), 4 nodes/block ----------------

__global__ __launch_bounds__(256) void k_l0_transform(
    const float* __restrict__ x,
    const float* __restrict__ Wl, const float* __restrict__ bl,
    const float* __restrict__ Wr, const float* __restrict__ br,
    unsigned short* __restrict__ xlb, float* __restrict__ xr) {
  int w = threadIdx.x >> 6, lane = threadIdx.x & 63;
  int n = blockIdx.x * 4 + w;
  if (n >= NN) return;
  int cb = lane << 2;
  float4 al = *(const float4*)&bl[cb];
  float4 ar = *(const float4*)&br[cb];
#pragma unroll
  for (int k = 0; k < INF_; ++k) {
    float xv = x[n * INF_ + k];
    float4 wl = *(const float4*)&Wl[k * HF + cb];
    float4 wr = *(const float4*)&Wr[k * HF + cb];
    al.x = fmaf(xv, wl.x, al.x); al.y = fmaf(xv, wl.y, al.y);
    al.z = fmaf(xv, wl.z, al.z); al.w = fmaf(xv, wl.w, al.w);
    ar.x = fmaf(xv, wr.x, ar.x); ar.y = fmaf(xv, wr.y, ar.y);
    ar.z = fmaf(xv, wr.z, ar.z); ar.w = fmaf(xv, wr.w, ar.w);
  }
  uint2 pk;
  pk.x = (unsigned)f2bf(al.x) | ((unsigned)f2bf(al.y) << 16);
  pk.y = (unsigned)f2bf(al.z) | ((unsigned)f2bf(al.w) << 16);
  *(uint2*)&xlb[(size_t)n * HF + cb] = pk;
  *(float4*)&xr[(size_t)n * HF + cb] = ar;
}

// ---------------- layer-1 transforms via MFMA ----------------

__global__ __launch_bounds__(256) void k_l1_mfma(
    const unsigned short* __restrict__ x1b,   // [NN][256] bf16
    const unsigned short* __restrict__ Wsw,   // swizzled, 256 KB
    const float* __restrict__ bl, const float* __restrict__ br,
    unsigned short* __restrict__ xlb, float* __restrict__ xr) {
  __shared__ union {
    unsigned short a[64][264];                // 33792 B
    float o[64][132];                         // 33792 B
  } sm;
  int t = threadIdx.x;
  int row0 = blockIdx.x * 64;
#pragma unroll
  for (int it = 0; it < 8; ++it) {
    int idx = it * 256 + t;
    int row = idx >> 5, c16 = idx & 31;
    int grow = row0 + row; if (grow >= NN) grow = NN - 1;
    *(uint4*)&sm.a[row][c16 * 8] = *(const uint4*)(x1b + (size_t)grow * HF + c16 * 8);
  }
  __syncthreads();

  int w = t >> 6, lane = t & 63;
  int quad = lane >> 4, ln = lane & 15;
  int y = blockIdx.y;                         // 0..3

  f32x4 acc[8];
#pragma unroll
  for (int i = 0; i < 8; ++i) acc[i] = (f32x4){0.f, 0.f, 0.f, 0.f};

  for (int kk8 = 0; kk8 < 8; ++kk8) {
    bf16x8 af = *(const bf16x8*)&sm.a[w * 16 + ln][kk8 * 32 + quad * 8];
#pragma unroll
    for (int nt = 0; nt < 8; ++nt) {
      bf16x8 bfr = *(const bf16x8*)&Wsw[(size_t)((((y * 8 + nt) * 8 + kk8) * 64) + lane) * 8];
      acc[nt] = __builtin_amdgcn_mfma_f32_16x16x32_bf16(af, bfr, acc[nt], 0, 0, 0);
    }
  }
  __syncthreads();                            // done with sm.a
#pragma unroll
  for (int nt = 0; nt < 8; ++nt)
#pragma unroll
    for (int rg = 0; rg < 4; ++rg)
      sm.o[w * 16 + quad * 4 + rg][nt * 16 + ln] = acc[nt][rg];
  __syncthreads();

  if (y < 2) {                                // bf16 -> xlb, cols y*128..+127
    int cb8 = (t & 15) * 8;
    int rsub = t >> 4;                        // 0..15
    int gcol = y * 128 + cb8;
    float4 b0 = *(const float4*)&bl[gcol];
    float4 b1 = *(const float4*)&bl[gcol + 4];
#pragma unroll
    for (int i = 0; i < 4; ++i) {
      int row = i * 16 + rsub;
      int grow = row0 + row;
      if (grow < NN) {
        unsigned h0 = f2bf(sm.o[row][cb8 + 0] + b0.x);
        unsigned h1 = f2bf(sm.o[row][cb8 + 1] + b0.y);
        unsigned h2 = f2bf(sm.o[row][cb8 + 2] + b0.z);
        unsigned h3 = f2bf(sm.o[row][cb8 + 3] + b0.w);
        unsigned h4 = f2bf(sm.o[row][cb8 + 4] + b1.x);
        unsigned h5 = f2bf(sm.o[row][cb8 + 5] + b1.y);
        unsigned h6 = f2bf(sm.o[row][cb8 + 6] + b1.z);
        unsigned h7 = f2bf(sm.o[row][cb8 + 7] + b1.w);
        uint4 pk;
        pk.x = h0 | (h1 << 16);
        pk.y = h2 | (h3 << 16);
        pk.z = h4 | (h5 << 16);
        pk.w = h6 | (h7 << 16);
        *(uint4*)&xlb[(size_t)grow * HF + gcol] = pk;
      }
    }
  } else {                                    // fp32 -> xr, cols (y-2)*128..+127
    int cb4 = (t & 31) * 4;
    int rsub = t >> 5;                        // 0..7
    int gcol = (y - 2) * 128 + cb4;
    float4 b4 = *(const float4*)&br[gcol];
#pragma unroll
    for (int i = 0; i < 8; ++i) {
      int row = i * 8 + rsub;
      int grow = row0 + row;
      if (grow < NN) {
        float4 v;
        v.x = sm.o[row][cb4 + 0] + b4.x;
        v.y = sm.o[row][cb4 + 1] + b4.y;
        v.z = sm.o[row][cb4 + 2] + b4.z;
        v.w = sm.o[row][cb4 + 3] + b4.w;
        *(float4*)&xr[(size_t)grow * HF + gcol] = v;
      }
    }
  }
}

// ---------------- fused GATv2: single-pass online-softmax, one WAVE per node ----------------
// rec[beg+e] read directly (all lanes same address -> broadcast transaction);
// depth-2 rec / depth-1 row software pipeline, clamped indices (branch-free).

template <bool L0>
__global__ __launch_bounds__(256) void k_agg(
    const unsigned short* __restrict__ xlb, const float* xr_,   // no restrict: x2out aliases
    const int* __restrict__ rowptr, const float4* __restrict__ rec,
    const float* __restrict__ att, const float* __restrict__ We,
    const float* __restrict__ bias,
    const float* __restrict__ x, const float* __restrict__ proj0,
    float* __restrict__ x1out, unsigned short* __restrict__ x1bout,
    const float* __restrict__ x1in, float* x2out) {
  int wid = (blockIdx.x * 256 + threadIdx.x) >> 6;
  if (wid >= NN) return;
  int lane = threadIdx.x & 63;
  int n = wid;
  int cb = lane << 2;                    // channel base (0..252)

  float4 xr4 = *(const float4*)&xr_[(size_t)n * HF + cb];
  float4 at4 = *(const float4*)&att[cb];
  float4 w04 = *(const float4*)&We[cb];
  float4 w14 = *(const float4*)&We[HF + cb];

  int beg = rowptr[n];
  int deg = rowptr[n + 1] - beg;         // includes self-loop slot; deg >= 1

  float mx = -3.4e38f, den = 0.f;
  float4 acc = make_float4(0.f, 0.f, 0.f, 0.f);

  int last = deg - 1;
  float4 rC = rec[beg];
  uint2  pC = *(const uint2*)&xlb[(size_t)__float_as_int(rC.x) * HF + cb];
  float4 rN = rec[beg + min(1, last)];

  for (int e = 0; e < deg; ++e) {
    float4 rNN = rec[beg + min(e + 2, last)];
    uint2  pN  = *(const uint2*)&xlb[(size_t)__float_as_int(rN.x) * HF + cb];

    float4 vC = bf2f4(pC);
    // base = xr + a0*We0 + a1*We1  (per-edge uniform a0,a1)
    float4 bse;
    bse.x = fmaf(rC.y, w04.x, fmaf(rC.z, w14.x, xr4.x));
    bse.y = fmaf(rC.y, w04.y, fmaf(rC.z, w14.y, xr4.y));
    bse.z = fmaf(rC.y, w04.z, fmaf(rC.z, w14.z, xr4.z));
    bse.w = fmaf(rC.y, w04.w, fmaf(rC.z, w14.w, xr4.w));
    float4 mm;
    mm.x = vC.x + bse.x; mm.y = vC.y + bse.y;
    mm.z = vC.z + bse.z; mm.w = vC.w + bse.w;
    mm.x = fmaxf(mm.x, 0.2f * mm.x);           // leaky_relu 0.2
    mm.y = fmaxf(mm.y, 0.2f * mm.y);
    mm.z = fmaxf(mm.z, 0.2f * mm.z);
    mm.w = fmaxf(mm.w, 0.2f * mm.w);
    float t = mm.x * at4.x;
    t = fmaf(mm.y, at4.y, t);
    t = fmaf(mm.z, at4.z, t);
    t = fmaf(mm.w, at4.w, t);
    // per-head reduction over the 16-lane group
    t += __shfl_xor(t, 1, 64);
    t += __shfl_xor(t, 2, 64);
    t += __shfl_xor(t, 4, 64);
    t += __shfl_xor(t, 8, 64);
    // online softmax update
    float mn  = fmaxf(mx, t);
    float sc_ = __expf(mx - mn);     // exp(-inf)=0 handles first edge
    float w   = __expf(t - mn);
    den   = fmaf(den, sc_, w);
    acc.x = fmaf(acc.x, sc_, w * vC.x);
    acc.y = fmaf(acc.y, sc_, w * vC.y);
    acc.z = fmaf(acc.z, sc_, w * vC.z);
    acc.w = fmaf(acc.w, sc_, w * vC.w);
    mx = mn;
    rC = rN; rN = rNN; pC = pN;
  }

  float inv = 1.0f / den;
  float4 b4 = *(const float4*)&bias[cb];
  float4 o;
  o.x = fmaf(acc.x, inv, b4.x);
  o.y = fmaf(acc.y, inv, b4.y);
  o.z = fmaf(acc.z, inv, b4.z);
  o.w = fmaf(acc.w, inv, b4.w);
  o.x = (o.x > 0.f) ? o.x : expm1f(o.x);            // elu
  o.y = (o.y > 0.f) ? o.y : expm1f(o.y);
  o.z = (o.z > 0.f) ? o.z : expm1f(o.z);
  o.w = (o.w > 0.f) ? o.w : expm1f(o.w);

  if (L0) {
    float4 rr = make_float4(0.f, 0.f, 0.f, 0.f);
#pragma unroll
    for (int k = 0; k < INF_; ++k) {
      float xv = x[n * INF_ + k];                    // wave-uniform -> scalar load
      float4 p = *(const float4*)&proj0[k * HF + cb];
      rr.x = fmaf(xv, p.x, rr.x);
      rr.y = fmaf(xv, p.y, rr.y);
      rr.z = fmaf(xv, p.z, rr.z);
      rr.w = fmaf(xv, p.w, rr.w);
    }
    o.x += rr.x; o.y += rr.y; o.z += rr.z; o.w += rr.w;
    *(float4*)&x1out[(size_t)n * HF + cb] = o;
    uint2 pk;                                        // bf16 copy feeds the MFMA transform
    pk.x = (unsigned)f2bf(o.x) | ((unsigned)f2bf(o.y) << 16);
    pk.y = (unsigned)f2bf(o.z) | ((unsigned)f2bf(o.w) << 16);
    *(uint2*)&x1bout[(size_t)n * HF + cb] = pk;
  } else {
    float4 x1v = *(const float4*)&x1in[(size_t)n * HF + cb];
    o.x += x1v.x; o.y += x1v.y; o.z += x1v.z; o.w += x1v.w;
    *(float4*)&x2out[(size_t)n * HF + cb] = o;       // aliases xr_ row n: safe (own row, after read)
  }
}

// ---------------- pre-pool MLP + graph pooling: z=elu(x2@Wp+bp); gpool += z ----------------
// batch is sorted: run-length compress atomics within each thread's 8 rows.

__global__ __launch_bounds__(256) void k_pool(
    const float* __restrict__ x2, const float* __restrict__ Wp,
    const float* __restrict__ bp, const int* __restrict__ batch,
    float* __restrict__ gpool) {
  __shared__ float xs[32 * HF];
  __shared__ int gid_s[32];
  int t = threadIdx.x;
  int row0 = blockIdx.x * 32;
  const float4* s4 = (const float4*)(x2 + (size_t)row0 * HF);
  float4* d4 = (float4*)xs;
#pragma unroll
  for (int i = 0; i < 8; ++i) d4[i * 256 + t] = s4[i * 256 + t];
  if (t < 32) gid_s[t] = batch[row0 + t];
  __syncthreads();
  int j = t & 63, rg = t >> 6;          // thread: col j, rows rg*8..rg*8+7
  float acc[8];
#pragma unroll
  for (int rr = 0; rr < 8; ++rr) acc[rr] = 0.f;
  for (int k4 = 0; k4 < HF / 4; ++k4) {
    float w0 = Wp[(k4 * 4 + 0) * FCD + j];
    float w1 = Wp[(k4 * 4 + 1) * FCD + j];
    float w2 = Wp[(k4 * 4 + 2) * FCD + j];
    float w3 = Wp[(k4 * 4 + 3) * FCD + j];
#pragma unroll
    for (int rr = 0; rr < 8; ++rr) {
      float4 xv = *(const float4*)&xs[(rg * 8 + rr) * HF + k4 * 4];
      acc[rr] = fmaf(xv.x, w0, acc[rr]);
      acc[rr] = fmaf(xv.y, w1, acc[rr]);
      acc[rr] = fmaf(xv.z, w2, acc[rr]);
      acc[rr] = fmaf(xv.w, w3, acc[rr]);
    }
  }
  float b = bp[j];
  int gprev = gid_s[rg * 8];
  float run = 0.f;
#pragma unroll
  for (int rr = 0; rr < 8; ++rr) {
    float a = acc[rr] + b;
    float z = (a > 0.f) ? a : expm1f(a);
    int g = gid_s[rg * 8 + rr];
    if (g != gprev) {
      atomicAdd(&gpool[gprev * FCD + j], run);
      run = 0.f; gprev = g;
    }
    run += z;
  }
  atomicAdd(&gpool[gprev * FCD + j], run);
}

// ---------------- final classifier: out[g,k] = (gpool[g]/cnt[g]) @ Wc + bc ----------------

__global__ void k_head(const float* __restrict__ gpool, const int* __restrict__ batch,
                       const float* __restrict__ Wc, const float* __restrict__ bc,
                       float* __restrict__ out) {
  int t = threadIdx.x;                 // 128 threads
  int g = t >> 1, k = t & 1;
  int lo = 0, hi = NN;
  while (lo < hi) { int mid = (lo + hi) >> 1; if (batch[mid] < g) lo = mid + 1; else hi = mid; }
  int c0 = lo;
  lo = 0; hi = NN;
  while (lo < hi) { int mid = (lo + hi) >> 1; if (batch[mid] < g + 1) lo = mid + 1; else hi = mid; }
  int c1 = lo;
  float inv = 1.0f / fmaxf((float)(c1 - c0), 1.0f);
  float a = bc[k];
  for (int j = 0; j < FCD; ++j)
    a = fmaf(gpool[g * FCD + j] * inv, Wc[j * NCD + k], a);
  out[g * NCD + k] = a;
}

// ---------------- launch ----------------

extern "C" void kernel_launch(void* const* d_in, const int* in_sizes, int n_in,
                              void* d_out, int out_size, void* d_ws, size_t ws_size,
                              hipStream_t stream) {
  const float* x    = (const float*)d_in[0];
  const int*   ei   = (const int*)d_in[1];    // [2,E] int
  const float* ea   = (const float*)d_in[2];  // [E,2]
  const int*   batch= (const int*)d_in[3];
  const float* Wl0  = (const float*)d_in[4];
  const float* bl0  = (const float*)d_in[5];
  const float* Wr0  = (const float*)d_in[6];
  const float* br0  = (const float*)d_in[7];
  const float* We0  = (const float*)d_in[8];
  const float* att0 = (const float*)d_in[9];
  const float* b0   = (const float*)d_in[10];
  const float* proj0= (const float*)d_in[11];
  const float* Wl1  = (const float*)d_in[12];
  const float* bl1  = (const float*)d_in[13];
  const float* Wr1  = (const float*)d_in[14];
  const float* br1  = (const float*)d_in[15];
  const float* We1  = (const float*)d_in[16];
  const float* att1 = (const float*)d_in[17];
  const float* b1   = (const float*)d_in[18];
  const float* Wp   = (const float*)d_in[19];
  const float* bp   = (const float*)d_in[20];
  const float* Wc   = (const float*)d_in[21];
  const float* bc   = (const float*)d_in[22];
  float* out = (float*)d_out;

  // workspace layout (all 16B aligned)
  char* ws = (char*)d_ws;
  size_t off = 0;
  int*   rowptr = (int*)(ws + off);   off += ((NN + 1) * 4 + 15) / 16 * 16;
  int*   cnt    = (int*)(ws + off);   off += (NN * 4 + 15) / 16 * 16;
  int*   cursor = (int*)(ws + off);   off += (NN * 4 + 15) / 16 * 16;
  float4* rec   = (float4*)(ws + off); off += (size_t)NE2 * 16;
  unsigned short* xlb = (unsigned short*)(ws + off); off += (size_t)NN * HF * 2;
  float* xr     = (float*)(ws + off); off += (size_t)NN * HF * 4;
  float* x1     = (float*)(ws + off); off += (size_t)NN * HF * 4;
  unsigned short* x1b = (unsigned short*)(ws + off); off += (size_t)NN * HF * 2;
  float* gpool  = (float*)(ws + off); off += NG * FCD * 4;
  int*   bsum   = (int*)(ws + off);   off += (NBS * 4 + 15) / 16 * 16;
  int*   boff   = (int*)(ws + off);   off += (NBS * 4 + 15) / 16 * 16;
  unsigned short* Wsw = (unsigned short*)(ws + off); off += 512 * 256 * 2;
  float* x2     = xr;                  // alias: safe (each wave writes only its own row, after reading it)
  (void)ws_size; (void)in_sizes; (void)n_in; (void)out_size;

  // zero accumulators (ws is poisoned 0xAA before every call)
  hipMemsetAsync(cnt, 0, NN * 4, stream);
  hipMemsetAsync(gpool, 0, NG * FCD * 4, stream);

  // CSR build + edge records + self-loop means
  k_count<<<(NE + 255) / 256, 256, 0, stream>>>(ei, cnt);
  k_scan1<<<NBS, 256, 0, stream>>>(cnt, bsum);
  k_scan2<<<1, 128, 0, stream>>>(bsum, boff);
  k_scan3<<<NBS, 256, 0, stream>>>(cnt, boff, rowptr, cursor);
  k_scatter<<<(NE + 255) / 256, 256, 0, stream>>>(ei, ea, cursor, rec);
  k_selfloop<<<(NN * 64 + 255) / 256, 256, 0, stream>>>(rowptr, rec);

  // weight convert
  k_wconv<<<512, 256, 0, stream>>>(Wl1, Wr1, Wsw);

  // layer 0
  k_l0_transform<<<(NN + 3) / 4, 256, 0, stream>>>(x, Wl0, bl0, Wr0, br0, xlb, xr);
  k_agg<true><<<(NN * 64 + 255) / 256, 256, 0, stream>>>(
      xlb, xr, rowptr, rec, att0, We0, b0, x, proj0, x1, x1b, nullptr, nullptr);

  // layer 1 transforms via MFMA
  k_l1_mfma<<<dim3((NN + 63) / 64, 4), 256, 0, stream>>>(x1b, Wsw, bl1, br1, xlb, xr);
  k_agg<false><<<(NN * 64 + 255) / 256, 256, 0, stream>>>(
      xlb, xr, rowptr, rec, att1, We1, b1, nullptr, nullptr, nullptr, nullptr, x1, x2);

  // pre-pool MLP + pooling, then classifier
  k_pool<<<NN / 32, 256, 0, stream>>>(x2, Wp, bp, batch, gpool);
  k_head<<<1, 128, 0, stream>>>(gpool, batch, Wc, bc, out);
}